// Round 5
// baseline (1563.619 us; speedup 1.0000x reference)
//
#include <hip/hip_runtime.h>
#include <hip/hip_bf16.h>

// ---- fixed problem geometry ----
#define S 2048
#define D 1024
#define NH 16
#define HD 64
#define NL 4
#define VOCAB 32000
#define DFF 4096
#define EPS_LN 1e-5f

typedef unsigned short ushortT;
typedef __attribute__((ext_vector_type(8))) short short8;
typedef __attribute__((ext_vector_type(4))) unsigned short ushort4v;
typedef __attribute__((ext_vector_type(4))) float f32x4;

__device__ __forceinline__ ushortT f2bf(float f) {
    unsigned u = __float_as_uint(f);
    u += 0x7FFFu + ((u >> 16) & 1u);   // round-to-nearest-even
    return (ushortT)(u >> 16);
}

// async global->LDS, 16 bytes per lane; LDS dest must be wave-uniform base + lane*16
__device__ __forceinline__ void gload_lds16(const ushortT* g, ushortT* l) {
    auto gp = (const __attribute__((address_space(1))) unsigned int*)(uintptr_t)g;
    auto lp = (__attribute__((address_space(3))) unsigned int*)(uintptr_t)l;
    __builtin_amdgcn_global_load_lds(gp, lp, 16, 0, 0);
}

__device__ __forceinline__ void cvt8(const float* s, ushortT* d) {
    float4 a = *(const float4*)s;
    float4 b = *(const float4*)(s + 4);
    short8 r;
    r[0] = (short)f2bf(a.x); r[1] = (short)f2bf(a.y);
    r[2] = (short)f2bf(a.z); r[3] = (short)f2bf(a.w);
    r[4] = (short)f2bf(b.x); r[5] = (short)f2bf(b.y);
    r[6] = (short)f2bf(b.z); r[7] = (short)f2bf(b.w);
    *(short8*)d = r;
}

// ---------------- embedding + positional (dual f32/bf16 out) ----------------
__global__ __launch_bounds__(256) void embed_kernel(
    const int* __restrict__ ids, const float* __restrict__ embed,
    const float* __restrict__ pos, float* __restrict__ hf, ushortT* __restrict__ hb)
{
    int i = blockIdx.x * 256 + threadIdx.x;
    int srow = i >> 10;
    int d = i & (D - 1);
    float v = embed[(size_t)ids[srow] * D + d] + pos[i];
    hf[i] = v;
    hb[i] = f2bf(v);
}

// ---------------- per-layer weight conversion f32 -> bf16 (packed) ----------------
__global__ __launch_bounds__(256) void convert_layer(
    const float* __restrict__ wq, const float* __restrict__ wk, const float* __restrict__ wv,
    const float* __restrict__ wo, const float* __restrict__ w1, const float* __restrict__ w2,
    const float* __restrict__ bq, const float* __restrict__ bk, const float* __restrict__ bv,
    int l, ushortT* __restrict__ wl, float* __restrict__ bqkv)
{
    constexpr int R = (D * D) / 8;   // 131072 units of 8 elements
    const int u = blockIdx.x * 256 + threadIdx.x;
    if (u < 12 * R) {
        const float* src;
        if (u < 3 * R) {
            int sub = u >> 17, off = u & (R - 1);
            const float* w = (sub == 0) ? wq : (sub == 1) ? wk : wv;
            src = w + (size_t)l * D * D + (size_t)off * 8;
        } else if (u < 4 * R) {
            src = wo + (size_t)l * D * D + (size_t)(u - 3 * R) * 8;
        } else if (u < 8 * R) {
            src = w1 + (size_t)l * 4 * D * D + (size_t)(u - 4 * R) * 8;
        } else {
            src = w2 + (size_t)l * 4 * D * D + (size_t)(u - 8 * R) * 8;
        }
        cvt8(src, wl + (size_t)u * 8);
    } else if (u < 12 * R + 384) {
        int i = u - 12 * R;
        int sub = i >> 7, off = (i & 127) * 8;
        const float* src = ((sub == 0) ? bq : (sub == 1) ? bk : bv) + (size_t)l * D + off;
        *(float4*)(bqkv + sub * D + off)     = *(const float4*)src;
        *(float4*)(bqkv + sub * D + off + 4) = *(const float4*)(src + 4);
    }
}

__global__ __launch_bounds__(256) void convert_flat(
    const float* __restrict__ src, ushortT* __restrict__ dst)
{
    const size_t u = (size_t)blockIdx.x * 256 + threadIdx.x;   // grid exactly covers n/8
    cvt8(src + u * 8, dst + u * 8);
}

// ---------------- bf16 NT GEMM (128xBN, 2-phase) -- used for o-proj / MLP2 ----------------
template<int BN, int OUTMODE, int RELU, int HASBIAS>
__global__ __launch_bounds__(256) void gemm_bf(
    const ushortT* __restrict__ A, const ushortT* __restrict__ B,
    const float* __restrict__ bias, void* __restrict__ Cn, void* __restrict__ Ct,
    int N, int K)
{
    constexpr int WN = BN / 2;
    constexpr int NCT = WN / 16;
    __shared__ alignas(16) ushortT As[128 * 32];
    __shared__ alignas(16) ushortT Bs[BN * 32];

    const int tid = threadIdx.x;
    const int id = blockIdx.x;
    const int brow = (id & 15) * 128;
    const int bcol = (id >> 4) * BN;
    const int lane = tid & 63, wid = tid >> 6;
    const int l15 = lane & 15, l4 = lane >> 4;
    const int wr = wid >> 1, wc = wid & 1;
    const int str = tid >> 2;
    const int stc = (tid & 3) * 8;

    f32x4 acc[4][NCT] = {};

    const ushortT* Ab = A + (size_t)(brow + str) * K + stc;
    const ushortT* Bb = B + (size_t)(bcol + str) * K + stc;
    ushortT* AsD = &As[tid * 8];
    ushortT* BsD = &Bs[tid * 8];

    const int nkb = K >> 5;
    for (int kb = 0; kb < nkb; ++kb) {
        const int ko = kb * 32;
        gload_lds16(Ab + ko, AsD);
        gload_lds16(Ab + ko + (size_t)64 * K, AsD + 2048);
        gload_lds16(Bb + ko, BsD);
        if (BN == 128) gload_lds16(Bb + ko + (size_t)64 * K, BsD + 2048);
        __syncthreads();

        short8 af[4], bfr[NCT];
        #pragma unroll
        for (int rt = 0; rt < 4; ++rt)
            af[rt] = *(const short8*)&As[(wr * 64 + rt * 16 + l15) * 32 + l4 * 8];
        #pragma unroll
        for (int ct = 0; ct < NCT; ++ct)
            bfr[ct] = *(const short8*)&Bs[(wc * WN + ct * 16 + l15) * 32 + l4 * 8];
        #pragma unroll
        for (int rt = 0; rt < 4; ++rt)
            #pragma unroll
            for (int ct = 0; ct < NCT; ++ct)
                acc[rt][ct] = __builtin_amdgcn_mfma_f32_16x16x32_bf16(af[rt], bfr[ct], acc[rt][ct], 0, 0, 0);
        __syncthreads();
    }

    #pragma unroll
    for (int rt = 0; rt < 4; ++rt) {
        const int crow0 = brow + wr * 64 + rt * 16 + l4 * 4;
        #pragma unroll
        for (int ct = 0; ct < NCT; ++ct) {
            const int ccol = bcol + wc * WN + ct * 16 + l15;
            const float bv = HASBIAS ? bias[ccol] : 0.0f;
            if (OUTMODE == 0) {
                float* C = (float*)Cn;
                #pragma unroll
                for (int j = 0; j < 4; ++j) {
                    float v = acc[rt][ct][j] + bv;
                    if (RELU) v = fmaxf(v, 0.0f);
                    C[(size_t)(crow0 + j) * N + ccol] = v;
                }
            } else if (OUTMODE == 1) {
                ushortT* C = (ushortT*)Cn;
                #pragma unroll
                for (int j = 0; j < 4; ++j) {
                    float v = acc[rt][ct][j] + bv;
                    if (RELU) v = fmaxf(v, 0.0f);
                    C[(size_t)(crow0 + j) * N + ccol] = f2bf(v);
                }
            } else {
                if (bcol < 2048) {
                    ushortT* C = (ushortT*)Cn;
                    #pragma unroll
                    for (int j = 0; j < 4; ++j)
                        C[(size_t)(crow0 + j) * 2048 + ccol] = f2bf(acc[rt][ct][j] + bv);
                } else {
                    ushortT* C = (ushortT*)Ct;
                    ushort4v wv_;
                    #pragma unroll
                    for (int j = 0; j < 4; ++j) wv_[j] = f2bf(acc[rt][ct][j] + bv);
                    *(ushort4v*)&C[(size_t)(ccol - 2048) * S + crow0] = wv_;
                }
            }
        }
    }
}

// ---------------- 256x256 8-phase GEMM (T1+T2+T3+T4+T5) ----------------
// C = A @ B^T (+bias); A[2048 x K], B[N x K] bf16. BM=BN=256, BK=64, 512 thr = 8 waves (2M x 4N).
// LDS 128KB: 2 buf x {A[256][64] | B[256][64]}, slot-XOR swizzle (inverse swizzle on global src).
// Per K-tile: 4 phases {12 ds_read_b128 | stage 1 half-tile (2 gloads) | s_barrier | lgkmcnt(0)
//   | setprio(1) 16 MFMA setprio(0) | [vmcnt(4) at p3] | s_barrier}.
// Stage schedule (tile t): p0->A1(t+1), p1->B1(t+1), p2->B0(t+2), p3->A0(t+2); each target
// region is provably dead (last reader's phase barrier precedes the stage issue).
template<int OUTMODE, int RELU, int HASBIAS>
__global__ __launch_bounds__(512) void gemm256(
    const ushortT* __restrict__ A, const ushortT* __restrict__ B,
    const float* __restrict__ bias, void* __restrict__ Cn, void* __restrict__ Ct,
    int N, int K)
{
    __shared__ alignas(128) ushortT lds[65536];   // 128 KiB

    const int tid = threadIdx.x;
    const int NB = N >> 8;
    const int bid = blockIdx.x;
    const int wgid = (bid & 7) * NB + (bid >> 3);   // XCD-chunked (grid % 8 == 0 always here)
    const int brow = (wgid & 7) << 8;               // M = 2048 -> 8 m-blocks, fastest
    const int bcol = (wgid >> 3) << 8;

    const int lane = tid & 63;
    const int wid = tid >> 6;
    const int l15 = lane & 15, l4 = lane >> 4;
    const int wm = wid >> 2, wn = wid & 3;          // 2 x 4 wave grid

    const int NT = K >> 6;

    // staging: thread i covers (row = i>>3 within 64-row group, phys slot = i&7);
    // global col pre-swizzled so that phys slot s of row r holds logical slot s^(r&7)
    const int srow = tid >> 3;
    const int scol = ((tid & 7) ^ (srow & 7)) * 8;
    const ushortT* Asrc = A + (size_t)(brow + srow) * K + scol;
    const ushortT* Bsrc = B + (size_t)(bcol + srow) * K + scol;

    auto stA = [&](int t, int h) {
        if (t < NT) {
            const int bb = t & 1;
            #pragma unroll
            for (int g = 0; g < 2; ++g)
                gload_lds16(Asrc + (size_t)(h * 128 + g * 64) * K + (size_t)t * 64,
                            &lds[bb * 32768 + h * 8192 + g * 4096 + tid * 8]);
        }
    };
    auto stB = [&](int t, int h) {
        if (t < NT) {
            const int bb = t & 1;
            #pragma unroll
            for (int g = 0; g < 2; ++g)
                gload_lds16(Bsrc + (size_t)(h * 128 + g * 64) * K + (size_t)t * 64,
                            &lds[bb * 32768 + 16384 + h * 8192 + g * 4096 + tid * 8]);
        }
    };

    f32x4 acc[2][2][4][2] = {};

    // prologue: tile0 fully + tile1's B0,A0 (issue order matters for vmcnt counting)
    stA(0, 0); stB(0, 0); stA(0, 1); stB(0, 1); stB(1, 0); stA(1, 0);
    asm volatile("s_waitcnt vmcnt(4)" ::: "memory");   // tile0's 4 halves resident
    __builtin_amdgcn_s_barrier();

#define PHASE(RC, CC, STAGE, TAILVM)                                               \
    {                                                                              \
        short8 af[4][2], bfr[2][2];                                                \
        _Pragma("unroll") for (int r16 = 0; r16 < 4; ++r16)                        \
        _Pragma("unroll") for (int kk = 0; kk < 2; ++kk)                           \
            af[r16][kk] = *(const short8*)&lds[b * 32768 +                         \
                ((RC) * 128 + wm * 64 + r16 * 16 + l15) * 64 +                     \
                ((((kk << 2) + l4) ^ (l15 & 7)) << 3)];                            \
        _Pragma("unroll") for (int c16 = 0; c16 < 2; ++c16)                        \
        _Pragma("unroll") for (int kk = 0; kk < 2; ++kk)                           \
            bfr[c16][kk] = *(const short8*)&lds[b * 32768 + 16384 +                \
                ((CC) * 128 + wn * 32 + c16 * 16 + l15) * 64 +                     \
                ((((kk << 2) + l4) ^ (l15 & 7)) << 3)];                            \
        STAGE;                                                                     \
        __builtin_amdgcn_s_barrier();                                              \
        asm volatile("s_waitcnt lgkmcnt(0)" ::: "memory");                         \
        __builtin_amdgcn_sched_barrier(0);                                         \
        __builtin_amdgcn_s_setprio(1);                                             \
        _Pragma("unroll") for (int kk = 0; kk < 2; ++kk)                           \
        _Pragma("unroll") for (int r16 = 0; r16 < 4; ++r16)                        \
        _Pragma("unroll") for (int c16 = 0; c16 < 2; ++c16)                        \
            acc[RC][CC][r16][c16] = __builtin_amdgcn_mfma_f32_16x16x32_bf16(       \
                af[r16][kk], bfr[c16][kk], acc[RC][CC][r16][c16], 0, 0, 0);        \
        __builtin_amdgcn_s_setprio(0);                                             \
        TAILVM;                                                                    \
        __builtin_amdgcn_s_barrier();                                              \
    }

    for (int t = 0; t < NT; ++t) {
        const int b = t & 1;
        PHASE(0, 0, stA(t + 1, 1), ((void)0));
        PHASE(1, 0, stB(t + 1, 1), ((void)0));
        PHASE(0, 1, stB(t + 2, 0), ((void)0));
        PHASE(1, 1, stA(t + 2, 0),
              if (t < NT - 2) { asm volatile("s_waitcnt vmcnt(4)" ::: "memory"); }
              else            { asm volatile("s_waitcnt vmcnt(0)" ::: "memory"); });
    }
#undef PHASE

    // epilogue: C/D layout col = lane&15, row = (lane>>4)*4 + j
    #pragma unroll
    for (int rc = 0; rc < 2; ++rc)
    #pragma unroll
    for (int cc = 0; cc < 2; ++cc)
    #pragma unroll
    for (int r16 = 0; r16 < 4; ++r16)
    #pragma unroll
    for (int c16 = 0; c16 < 2; ++c16) {
        const int crow0 = brow + rc * 128 + wm * 64 + r16 * 16 + l4 * 4;
        const int ccol  = bcol + cc * 128 + wn * 32 + c16 * 16 + l15;
        const float bv = HASBIAS ? bias[ccol] : 0.0f;
        if (OUTMODE == 0) {
            float* C = (float*)Cn;
            #pragma unroll
            for (int j = 0; j < 4; ++j) {
                float v = acc[rc][cc][r16][c16][j] + bv;
                if (RELU) v = fmaxf(v, 0.0f);
                __builtin_nontemporal_store(v, &C[(size_t)(crow0 + j) * N + ccol]);
            }
        } else if (OUTMODE == 1) {
            ushortT* C = (ushortT*)Cn;
            #pragma unroll
            for (int j = 0; j < 4; ++j) {
                float v = acc[rc][cc][r16][c16][j] + bv;
                if (RELU) v = fmaxf(v, 0.0f);
                C[(size_t)(crow0 + j) * N + ccol] = f2bf(v);
            }
        } else {
            if (ccol < 2048) {   // q,k region -> [S][2048]
                ushortT* C = (ushortT*)Cn;
                #pragma unroll
                for (int j = 0; j < 4; ++j)
                    C[(size_t)(crow0 + j) * 2048 + ccol] = f2bf(acc[rc][cc][r16][c16][j] + bv);
            } else {             // v region -> transposed [D][S]
                ushortT* C = (ushortT*)Ct;
                ushort4v wv_;
                #pragma unroll
                for (int j = 0; j < 4; ++j) wv_[j] = f2bf(acc[rc][cc][r16][c16][j] + bv);
                *(ushort4v*)&C[(size_t)(ccol - 2048) * S + crow0] = wv_;
            }
        }
    }
}

// ---------------- flash attention (causal), bf16 in/out ----------------
__global__ __launch_bounds__(256) void attn_kernel(
    const ushortT* __restrict__ qk, const ushortT* __restrict__ vt,
    ushortT* __restrict__ att)
{
    const int h = blockIdx.y;
    const int q0 = blockIdx.x * 64;
    const int tid = threadIdx.x;
    const int w = tid >> 6, lane = tid & 63;
    const int l15 = lane & 15, l4 = lane >> 4;
    const int qrow0 = q0 + w * 16;

    __shared__ short p_lds[4][16][48];

    short8 aq[2];
    {
        const ushortT* qp = qk + (size_t)(qrow0 + l15) * 2048 + h * HD + l4 * 8;
        aq[0] = *(const short8*)qp;
        aq[1] = *(const short8*)(qp + 32);
    }

    f32x4 o[4] = {};
    float mrow[4], lrow[4];
    #pragma unroll
    for (int j = 0; j < 4; ++j) { mrow[j] = -1e30f; lrow[j] = 0.0f; }

    const int nkb = blockIdx.x * 2 + 2;
    for (int kb32 = 0; kb32 < nkb; ++kb32) {
        const int kb = kb32 * 32;
        f32x4 s[2] = {};
        #pragma unroll
        for (int kh = 0; kh < 2; ++kh) {
            const ushortT* kp = qk + (size_t)(kb + kh * 16 + l15) * 2048 + 1024 + h * HD + l4 * 8;
            short8 b0 = *(const short8*)kp;
            short8 b1 = *(const short8*)(kp + 32);
            s[kh] = __builtin_amdgcn_mfma_f32_16x16x32_bf16(aq[0], b0, s[kh], 0, 0, 0);
            s[kh] = __builtin_amdgcn_mfma_f32_16x16x32_bf16(aq[1], b1, s[kh], 0, 0, 0);
        }
        float fac[4];
        #pragma unroll
        for (int j = 0; j < 4; ++j) {
            const int qg = qrow0 + l4 * 4 + j;
            float v0 = s[0][j] * 0.125f;
            float v1 = s[1][j] * 0.125f;
            if (kb + l15 > qg)      v0 = -1e30f;
            if (kb + 16 + l15 > qg) v1 = -1e30f;
            float bm = fmaxf(v0, v1);
            #pragma unroll
            for (int d_ = 1; d_ < 16; d_ <<= 1) bm = fmaxf(bm, __shfl_xor(bm, d_, 64));
            const float mnew = fmaxf(mrow[j], bm);
            const float f = __expf(mrow[j] - mnew);
            const float p0 = __expf(v0 - mnew);
            const float p1 = __expf(v1 - mnew);
            s[0][j] = p0; s[1][j] = p1;
            float rs = p0 + p1;
            #pragma unroll
            for (int d_ = 1; d_ < 16; d_ <<= 1) rs += __shfl_xor(rs, d_, 64);
            lrow[j] = lrow[j] * f + rs;
            mrow[j] = mnew;
            fac[j] = f;
        }
        #pragma unroll
        for (int c = 0; c < 4; ++c)
            #pragma unroll
            for (int j = 0; j < 4; ++j) o[c][j] *= fac[j];

        #pragma unroll
        for (int kh = 0; kh < 2; ++kh)
            #pragma unroll
            for (int j = 0; j < 4; ++j)
                p_lds[w][l4 * 4 + j][kh * 16 + l15] = (short)f2bf(s[kh][j]);
        __syncthreads();
        short8 pa = *(const short8*)&p_lds[w][l15][l4 * 8];

        #pragma unroll
        for (int c = 0; c < 4; ++c) {
            short8 bv = *(const short8*)(vt + (size_t)(h * HD + c * 16 + l15) * S + kb + l4 * 8);
            o[c] = __builtin_amdgcn_mfma_f32_16x16x32_bf16(pa, bv, o[c], 0, 0, 0);
        }
        __syncthreads();
    }

    #pragma unroll
    for (int c = 0; c < 4; ++c)
        #pragma unroll
        for (int j = 0; j < 4; ++j)
            att[(size_t)(qrow0 + l4 * 4 + j) * D + h * HD + c * 16 + l15] = f2bf(o[c][j] / lrow[j]);
}

// ---------------- fused residual + LayerNorm, dual f32/bf16 out ----------------
__global__ __launch_bounds__(256) void ln_kernel(
    const float* __restrict__ a, const float* __restrict__ b,
    const float* __restrict__ g, const float* __restrict__ bb,
    float* __restrict__ yf, ushortT* __restrict__ yb)
{
    const int row = blockIdx.x;
    const int tid = threadIdx.x;
    const size_t base = (size_t)row * D;
    float x[4]; float s = 0.f, s2 = 0.f;
    #pragma unroll
    for (int i = 0; i < 4; ++i) {
        const int c = tid + i * 256;
        x[i] = a[base + c] + b[base + c];
        s += x[i]; s2 += x[i] * x[i];
    }
    #pragma unroll
    for (int d_ = 1; d_ < 64; d_ <<= 1) {
        s  += __shfl_xor(s,  d_, 64);
        s2 += __shfl_xor(s2, d_, 64);
    }
    __shared__ float rs[4], rs2[4];
    const int wid = tid >> 6, lane = tid & 63;
    if (lane == 0) { rs[wid] = s; rs2[wid] = s2; }
    __syncthreads();
    s = rs[0] + rs[1] + rs[2] + rs[3];
    s2 = rs2[0] + rs2[1] + rs2[2] + rs2[3];
    const float mu = s * (1.0f / D);
    const float var = s2 * (1.0f / D) - mu * mu;
    const float inv = rsqrtf(var + EPS_LN);
    #pragma unroll
    for (int i = 0; i < 4; ++i) {
        const int c = tid + i * 256;
        float v = (x[i] - mu) * inv * g[c] + bb[c];
        yf[base + c] = v;
        yb[base + c] = f2bf(v);
    }
}

// ---------------- launch ----------------
extern "C" void kernel_launch(void* const* d_in, const int* in_sizes, int n_in,
                              void* d_out, int out_size, void* d_ws, size_t ws_size,
                              hipStream_t stream) {
    const int*   ids   = (const int*)  d_in[0];
    const float* emb   = (const float*)d_in[1];
    const float* pos   = (const float*)d_in[2];
    const float* wq    = (const float*)d_in[3];
    const float* bq    = (const float*)d_in[4];
    const float* wk    = (const float*)d_in[5];
    const float* bk    = (const float*)d_in[6];
    const float* wv    = (const float*)d_in[7];
    const float* bv    = (const float*)d_in[8];
    const float* wo    = (const float*)d_in[9];
    const float* bo    = (const float*)d_in[10];
    const float* ln1g  = (const float*)d_in[11];
    const float* ln1b  = (const float*)d_in[12];
    const float* w1    = (const float*)d_in[13];
    const float* b1    = (const float*)d_in[14];
    const float* w2    = (const float*)d_in[15];
    const float* b2    = (const float*)d_in[16];
    const float* ln2g  = (const float*)d_in[17];
    const float* ln2b  = (const float*)d_in[18];
    const float* lmh   = (const float*)d_in[19];
    float* out = (float*)d_out;

    const size_t MB = 1024 * 1024;
    char* w = (char*)d_ws;
    float*   h_f32   = (float*)(w);              //  8 MB  residual stream
    float*   h2_f32  = (float*)(w +  8 * MB);    //  8 MB  post-LN1 residual
    float*   om2_f32 = (float*)(w + 16 * MB);    //  8 MB  o-proj out, then MLP2 out
    ushortT* h_bf    = (ushortT*)(w + 24 * MB);  //  4 MB
    ushortT* h2_bf   = (ushortT*)(w + 28 * MB);  //  4 MB
    ushortT* qk_bf   = (ushortT*)(w + 32 * MB);  //  8 MB  [S][2048]
    ushortT* vt_bf   = (ushortT*)(w + 40 * MB);  //  4 MB  [1024][S]
    ushortT* att_bf  = (ushortT*)(w + 44 * MB);  //  4 MB
    ushortT* m1_bf   = (ushortT*)(w + 48 * MB);  // 16 MB  [S][4096]
    ushortT* wl      = (ushortT*)(w + 64 * MB);  // 24 MB  per-layer bf16 weights
    float*   bqkv    = (float*)(w + 88 * MB);    // 12 KB  packed qkv bias
    ushortT* lmh_bf  = (ushortT*)(w + 89 * MB);  // 65.5 MB

    ushortT* wqkv_bf = wl;
    ushortT* wo_bf   = wl + (size_t)3 * D * D;
    ushortT* w1_bf   = wl + (size_t)4 * D * D;
    ushortT* w2_bf   = wl + (size_t)8 * D * D;

    embed_kernel<<<(S * D) / 256, 256, 0, stream>>>(ids, emb, pos, h_f32, h_bf);

    for (int l = 0; l < NL; ++l) {
        convert_layer<<<6146, 256, 0, stream>>>(wq, wk, wv, wo, w1, w2, bq, bk, bv, l, wl, bqkv);

        // fused QKV: [S x 3072] = h_bf @ wqkv^T ; q,k -> qk_bf, v -> vt_bf (transposed)
        gemm256<2, 0, 1><<<8 * 12, 512, 0, stream>>>(h_bf, wqkv_bf, bqkv, qk_bf, vt_bf, 3072, D);

        attn_kernel<<<dim3(S / 64, NH), 256, 0, stream>>>(qk_bf, vt_bf, att_bf);

        gemm_bf<64, 0, 0, 1><<<16 * 16, 256, 0, stream>>>(att_bf, wo_bf, bo + (size_t)l * D, om2_f32, nullptr, D, D);
        ln_kernel<<<S, 256, 0, stream>>>(h_f32, om2_f32, ln1g + (size_t)l * D, ln1b + (size_t)l * D, h2_f32, h2_bf);

        gemm256<1, 1, 1><<<8 * 16, 512, 0, stream>>>(h2_bf, w1_bf, b1 + (size_t)l * DFF, m1_bf, nullptr, DFF, D);
        gemm_bf<64, 0, 0, 1><<<16 * 16, 256, 0, stream>>>(m1_bf, w2_bf, b2 + (size_t)l * D, om2_f32, nullptr, D, DFF);
        ln_kernel<<<S, 256, 0, stream>>>(h2_f32, om2_f32, ln2g + (size_t)l * D, ln2b + (size_t)l * D, h_f32, h_bf);
    }

    convert_flat<<<(VOCAB * D) / (256 * 8), 256, 0, stream>>>(lmh, lmh_bf);
    gemm256<0, 0, 0><<<8 * 125, 512, 0, stream>>>(h_bf, lmh_bf, nullptr, out, nullptr, VOCAB, D);
}

// Round 6
// 1337.416 us; speedup vs baseline: 1.1691x; 1.1691x over previous
//
#include <hip/hip_runtime.h>
#include <hip/hip_bf16.h>

// ---- fixed problem geometry ----
#define S 2048
#define D 1024
#define NH 16
#define HD 64
#define NL 4
#define VOCAB 32000
#define DFF 4096
#define EPS_LN 1e-5f

typedef unsigned short ushortT;
typedef __attribute__((ext_vector_type(8))) short short8;
typedef __attribute__((ext_vector_type(4))) unsigned short ushort4v;
typedef __attribute__((ext_vector_type(4))) float f32x4;

__device__ __forceinline__ ushortT f2bf(float f) {
    unsigned u = __float_as_uint(f);
    u += 0x7FFFu + ((u >> 16) & 1u);   // round-to-nearest-even
    return (ushortT)(u >> 16);
}

// async global->LDS, 16 bytes per lane; LDS dest must be wave-uniform base + lane*16
__device__ __forceinline__ void gload_lds16(const ushortT* g, ushortT* l) {
    auto gp = (const __attribute__((address_space(1))) unsigned int*)(uintptr_t)g;
    auto lp = (__attribute__((address_space(3))) unsigned int*)(uintptr_t)l;
    __builtin_amdgcn_global_load_lds(gp, lp, 16, 0, 0);
}

__device__ __forceinline__ void cvt8(const float* s, ushortT* d) {
    float4 a = *(const float4*)s;
    float4 b = *(const float4*)(s + 4);
    short8 r;
    r[0] = (short)f2bf(a.x); r[1] = (short)f2bf(a.y);
    r[2] = (short)f2bf(a.z); r[3] = (short)f2bf(a.w);
    r[4] = (short)f2bf(b.x); r[5] = (short)f2bf(b.y);
    r[6] = (short)f2bf(b.z); r[7] = (short)f2bf(b.w);
    *(short8*)d = r;
}

// ---------------- embedding + positional (dual f32/bf16 out) ----------------
__global__ __launch_bounds__(256) void embed_kernel(
    const int* __restrict__ ids, const float* __restrict__ embed,
    const float* __restrict__ pos, float* __restrict__ hf, ushortT* __restrict__ hb)
{
    int i = blockIdx.x * 256 + threadIdx.x;
    int srow = i >> 10;
    int d = i & (D - 1);
    float v = embed[(size_t)ids[srow] * D + d] + pos[i];
    hf[i] = v;
    hb[i] = f2bf(v);
}

// ---------------- per-layer weight conversion f32 -> bf16 (packed) ----------------
__global__ __launch_bounds__(256) void convert_layer(
    const float* __restrict__ wq, const float* __restrict__ wk, const float* __restrict__ wv,
    const float* __restrict__ wo, const float* __restrict__ w1, const float* __restrict__ w2,
    const float* __restrict__ bq, const float* __restrict__ bk, const float* __restrict__ bv,
    int l, ushortT* __restrict__ wl, float* __restrict__ bqkv)
{
    constexpr int R = (D * D) / 8;   // 131072 units of 8 elements
    const int u = blockIdx.x * 256 + threadIdx.x;
    if (u < 12 * R) {
        const float* src;
        if (u < 3 * R) {
            int sub = u >> 17, off = u & (R - 1);
            const float* w = (sub == 0) ? wq : (sub == 1) ? wk : wv;
            src = w + (size_t)l * D * D + (size_t)off * 8;
        } else if (u < 4 * R) {
            src = wo + (size_t)l * D * D + (size_t)(u - 3 * R) * 8;
        } else if (u < 8 * R) {
            src = w1 + (size_t)l * 4 * D * D + (size_t)(u - 4 * R) * 8;
        } else {
            src = w2 + (size_t)l * 4 * D * D + (size_t)(u - 8 * R) * 8;
        }
        cvt8(src, wl + (size_t)u * 8);
    } else if (u < 12 * R + 384) {
        int i = u - 12 * R;
        int sub = i >> 7, off = (i & 127) * 8;
        const float* src = ((sub == 0) ? bq : (sub == 1) ? bk : bv) + (size_t)l * D + off;
        *(float4*)(bqkv + sub * D + off)     = *(const float4*)src;
        *(float4*)(bqkv + sub * D + off + 4) = *(const float4*)(src + 4);
    }
}

__global__ __launch_bounds__(256) void convert_flat(
    const float* __restrict__ src, ushortT* __restrict__ dst)
{
    const size_t u = (size_t)blockIdx.x * 256 + threadIdx.x;   // grid exactly covers n/8
    cvt8(src + u * 8, dst + u * 8);
}

// ---------------- bf16 NT GEMM (128xBN, 2-phase) ----------------
template<int BN, int OUTMODE, int RELU, int HASBIAS>
__global__ __launch_bounds__(256) void gemm_bf(
    const ushortT* __restrict__ A, const ushortT* __restrict__ B,
    const float* __restrict__ bias, void* __restrict__ Cn, void* __restrict__ Ct,
    int N, int K)
{
    constexpr int WN = BN / 2;
    constexpr int NCT = WN / 16;
    __shared__ alignas(16) ushortT As[128 * 32];
    __shared__ alignas(16) ushortT Bs[BN * 32];

    const int tid = threadIdx.x;
    const int id = blockIdx.x;
    const int brow = (id & 15) * 128;
    const int bcol = (id >> 4) * BN;
    const int lane = tid & 63, wid = tid >> 6;
    const int l15 = lane & 15, l4 = lane >> 4;
    const int wr = wid >> 1, wc = wid & 1;
    const int str = tid >> 2;
    const int stc = (tid & 3) * 8;

    f32x4 acc[4][NCT] = {};

    const ushortT* Ab = A + (size_t)(brow + str) * K + stc;
    const ushortT* Bb = B + (size_t)(bcol + str) * K + stc;
    ushortT* AsD = &As[tid * 8];
    ushortT* BsD = &Bs[tid * 8];

    const int nkb = K >> 5;
    for (int kb = 0; kb < nkb; ++kb) {
        const int ko = kb * 32;
        gload_lds16(Ab + ko, AsD);
        gload_lds16(Ab + ko + (size_t)64 * K, AsD + 2048);
        gload_lds16(Bb + ko, BsD);
        if (BN == 128) gload_lds16(Bb + ko + (size_t)64 * K, BsD + 2048);
        __syncthreads();

        short8 af[4], bfr[NCT];
        #pragma unroll
        for (int rt = 0; rt < 4; ++rt)
            af[rt] = *(const short8*)&As[(wr * 64 + rt * 16 + l15) * 32 + l4 * 8];
        #pragma unroll
        for (int ct = 0; ct < NCT; ++ct)
            bfr[ct] = *(const short8*)&Bs[(wc * WN + ct * 16 + l15) * 32 + l4 * 8];
        #pragma unroll
        for (int rt = 0; rt < 4; ++rt)
            #pragma unroll
            for (int ct = 0; ct < NCT; ++ct)
                acc[rt][ct] = __builtin_amdgcn_mfma_f32_16x16x32_bf16(af[rt], bfr[ct], acc[rt][ct], 0, 0, 0);
        __syncthreads();
    }

    #pragma unroll
    for (int rt = 0; rt < 4; ++rt) {
        const int crow0 = brow + wr * 64 + rt * 16 + l4 * 4;
        #pragma unroll
        for (int ct = 0; ct < NCT; ++ct) {
            const int ccol = bcol + wc * WN + ct * 16 + l15;
            const float bv = HASBIAS ? bias[ccol] : 0.0f;
            if (OUTMODE == 0) {
                float* C = (float*)Cn;
                #pragma unroll
                for (int j = 0; j < 4; ++j) {
                    float v = acc[rt][ct][j] + bv;
                    if (RELU) v = fmaxf(v, 0.0f);
                    C[(size_t)(crow0 + j) * N + ccol] = v;
                }
            } else if (OUTMODE == 1) {
                ushortT* C = (ushortT*)Cn;
                #pragma unroll
                for (int j = 0; j < 4; ++j) {
                    float v = acc[rt][ct][j] + bv;
                    if (RELU) v = fmaxf(v, 0.0f);
                    C[(size_t)(crow0 + j) * N + ccol] = f2bf(v);
                }
            } else {
                if (bcol < 2048) {
                    ushortT* C = (ushortT*)Cn;
                    #pragma unroll
                    for (int j = 0; j < 4; ++j)
                        C[(size_t)(crow0 + j) * 2048 + ccol] = f2bf(acc[rt][ct][j] + bv);
                } else {
                    ushortT* C = (ushortT*)Ct;
                    ushort4v wv_;
                    #pragma unroll
                    for (int j = 0; j < 4; ++j) wv_[j] = f2bf(acc[rt][ct][j] + bv);
                    *(ushort4v*)&C[(size_t)(ccol - 2048) * S + crow0] = wv_;
                }
            }
        }
    }
}

// ---------------- 256x256 8-phase GEMM, fragment-reuse schedule ----------------
// Per K-tile (BK=64): p0 reads A0+B0 -> MFMA(0,0); p1 reads B1 -> (0,1) [A0 live];
// p2 reads A1 -> (1,1) [B1 live]; p3 reads nothing -> (1,0) [A1,B0 live].
// 24 ds_read_b128/tile/wave (vs 48 naive). Stages: p0->A1(t+1), p1->B1(t+1),
// p2->B0(t+2), p3->A0(t+2); vmcnt(4) once per tile (counted, never 0 mid-loop).
template<int OUTMODE, int RELU, int HASBIAS>
__global__ __launch_bounds__(512) void gemm256(
    const ushortT* __restrict__ A, const ushortT* __restrict__ B,
    const float* __restrict__ bias, void* __restrict__ Cn, void* __restrict__ Ct,
    int N, int K)
{
    __shared__ alignas(128) ushortT lds[65536];   // 128 KiB

    const int tid = threadIdx.x;
    const int NB = N >> 8;
    const int bid = blockIdx.x;
    const int wgid = (bid & 7) * NB + (bid >> 3);   // XCD-chunked (grid % 8 == 0 here)
    const int brow = (wgid & 7) << 8;               // M = 2048 -> 8 m-blocks, fastest
    const int bcol = (wgid >> 3) << 8;

    const int lane = tid & 63;
    const int wid = tid >> 6;
    const int l15 = lane & 15, l4 = lane >> 4;
    const int wm = wid >> 2, wn = wid & 3;          // 2 x 4 wave grid

    const int NT = K >> 6;

    // staging: thread i -> (row = i>>3 within 64-row group, phys slot = i&7);
    // global col pre-swizzled: phys slot s of row r holds logical slot s^(r&7)
    const int srow = tid >> 3;
    const int scol = ((tid & 7) ^ (srow & 7)) * 8;
    const ushortT* Asrc = A + (size_t)(brow + srow) * K + scol;
    const ushortT* Bsrc = B + (size_t)(bcol + srow) * K + scol;

    auto stA = [&](int t, int h) {
        if (t < NT) {
            const int bb = t & 1;
            #pragma unroll
            for (int g = 0; g < 2; ++g)
                gload_lds16(Asrc + (size_t)(h * 128 + g * 64) * K + (size_t)t * 64,
                            &lds[bb * 32768 + h * 8192 + g * 4096 + tid * 8]);
        }
    };
    auto stB = [&](int t, int h) {
        if (t < NT) {
            const int bb = t & 1;
            #pragma unroll
            for (int g = 0; g < 2; ++g)
                gload_lds16(Bsrc + (size_t)(h * 128 + g * 64) * K + (size_t)t * 64,
                            &lds[bb * 32768 + 16384 + h * 8192 + g * 4096 + tid * 8]);
        }
    };

    f32x4 acc[2][2][4][2] = {};

    // prologue: tile0 fully + tile1's B0,A0
    stA(0, 0); stB(0, 0); stA(0, 1); stB(0, 1); stB(1, 0); stA(1, 0);
    asm volatile("s_waitcnt vmcnt(4)" ::: "memory");   // tile0's 4 halves resident
    __builtin_amdgcn_s_barrier();

#define RD_A(DST, RC)                                                          \
    _Pragma("unroll") for (int r16 = 0; r16 < 4; ++r16)                        \
    _Pragma("unroll") for (int kk = 0; kk < 2; ++kk)                           \
        DST[r16][kk] = *(const short8*)&lds[b * 32768 +                        \
            (((RC) * 128 + wm * 64 + r16 * 16 + l15) << 6) +                   \
            ((((kk << 2) + l4) ^ (l15 & 7)) << 3)];
#define RD_B(DST, CC)                                                          \
    _Pragma("unroll") for (int c16 = 0; c16 < 2; ++c16)                        \
    _Pragma("unroll") for (int kk = 0; kk < 2; ++kk)                           \
        DST[c16][kk] = *(const short8*)&lds[b * 32768 + 16384 +                \
            (((CC) * 128 + wn * 32 + c16 * 16 + l15) << 6) +                   \
            ((((kk << 2) + l4) ^ (l15 & 7)) << 3)];
#define MFMA_Q(AF, BF, RC, CC)                                                 \
    __builtin_amdgcn_s_setprio(1);                                             \
    _Pragma("unroll") for (int kk = 0; kk < 2; ++kk)                           \
    _Pragma("unroll") for (int r16 = 0; r16 < 4; ++r16)                        \
    _Pragma("unroll") for (int c16 = 0; c16 < 2; ++c16)                        \
        acc[RC][CC][r16][c16] = __builtin_amdgcn_mfma_f32_16x16x32_bf16(       \
            AF[r16][kk], BF[c16][kk], acc[RC][CC][r16][c16], 0, 0, 0);         \
    __builtin_amdgcn_s_setprio(0);
#define WAIT_LGKM                                                              \
    asm volatile("s_waitcnt lgkmcnt(0)" ::: "memory");                         \
    __builtin_amdgcn_sched_barrier(0);

    for (int t = 0; t < NT; ++t) {
        const int b = t & 1;
        short8 a_[4][2], b0[2][2], b1[2][2];

        // p0: (0,0)
        RD_A(a_, 0); RD_B(b0, 0);
        stA(t + 1, 1);
        __builtin_amdgcn_s_barrier();
        WAIT_LGKM;
        MFMA_Q(a_, b0, 0, 0);
        __builtin_amdgcn_s_barrier();

        // p1: (0,1), A0 still in regs
        RD_B(b1, 1);
        stB(t + 1, 1);
        __builtin_amdgcn_s_barrier();
        WAIT_LGKM;
        MFMA_Q(a_, b1, 0, 1);
        __builtin_amdgcn_s_barrier();

        // p2: (1,1), overwrite a_ with A1 (A0 dead)
        RD_A(a_, 1);
        stB(t + 2, 0);
        __builtin_amdgcn_s_barrier();
        WAIT_LGKM;
        MFMA_Q(a_, b1, 1, 1);
        __builtin_amdgcn_s_barrier();

        // p3: (1,0), no new reads (A1, B0 live)
        stA(t + 2, 0);
        __builtin_amdgcn_s_barrier();
        MFMA_Q(a_, b0, 1, 0);
        if (t < NT - 2) { asm volatile("s_waitcnt vmcnt(4)" ::: "memory"); }
        else            { asm volatile("s_waitcnt vmcnt(0)" ::: "memory"); }
        __builtin_amdgcn_s_barrier();
    }
#undef RD_A
#undef RD_B
#undef MFMA_Q
#undef WAIT_LGKM

    // epilogue: C/D layout col = lane&15, row = (lane>>4)*4 + j
    #pragma unroll
    for (int rc = 0; rc < 2; ++rc)
    #pragma unroll
    for (int cc = 0; cc < 2; ++cc)
    #pragma unroll
    for (int r16 = 0; r16 < 4; ++r16)
    #pragma unroll
    for (int c16 = 0; c16 < 2; ++c16) {
        const int crow0 = brow + rc * 128 + wm * 64 + r16 * 16 + l4 * 4;
        const int ccol  = bcol + cc * 128 + wn * 32 + c16 * 16 + l15;
        const float bv = HASBIAS ? bias[ccol] : 0.0f;
        if (OUTMODE == 0) {
            float* C = (float*)Cn;
            #pragma unroll
            for (int j = 0; j < 4; ++j) {
                float v = acc[rc][cc][r16][c16][j] + bv;
                if (RELU) v = fmaxf(v, 0.0f);
                __builtin_nontemporal_store(v, &C[(size_t)(crow0 + j) * N + ccol]);
            }
        } else if (OUTMODE == 1) {
            ushortT* C = (ushortT*)Cn;
            #pragma unroll
            for (int j = 0; j < 4; ++j) {
                float v = acc[rc][cc][r16][c16][j] + bv;
                if (RELU) v = fmaxf(v, 0.0f);
                C[(size_t)(crow0 + j) * N + ccol] = f2bf(v);
            }
        } else {
            if (ccol < 2048) {
                ushortT* C = (ushortT*)Cn;
                #pragma unroll
                for (int j = 0; j < 4; ++j)
                    C[(size_t)(crow0 + j) * 2048 + ccol] = f2bf(acc[rc][cc][r16][c16][j] + bv);
            } else {
                ushortT* C = (ushortT*)Ct;
                ushort4v wv_;
                #pragma unroll
                for (int j = 0; j < 4; ++j) wv_[j] = f2bf(acc[rc][cc][r16][c16][j] + bv);
                *(ushort4v*)&C[(size_t)(ccol - 2048) * S + crow0] = wv_;
            }
        }
    }
}

// ---------------- flash attention (causal), bf16 in/out, barrier-free ----------------
// qk: [S][2048] (q cols 0..1023, k cols 1024..2047); vt: [1024][S] transposed V
// grid (S/64, NH); 4 waves, wave w owns q rows [q0+16w, q0+16w+16).
// p_lds is strictly per-wave -> no block barriers; compiler's lgkmcnt ordering suffices.
__global__ __launch_bounds__(256) void attn_kernel(
    const ushortT* __restrict__ qk, const ushortT* __restrict__ vt,
    ushortT* __restrict__ att)
{
    const int h = blockIdx.y;
    const int q0 = blockIdx.x * 64;
    const int tid = threadIdx.x;
    const int w = tid >> 6, lane = tid & 63;
    const int l15 = lane & 15, l4 = lane >> 4;
    const int qrow0 = q0 + w * 16;

    __shared__ short p_lds[4][16][48];

    short8 aq[2];
    {
        const ushortT* qp = qk + (size_t)(qrow0 + l15) * 2048 + h * HD + l4 * 8;
        aq[0] = *(const short8*)qp;
        aq[1] = *(const short8*)(qp + 32);
    }

    f32x4 o[4] = {};
    float mrow[4], lrow[4];
    #pragma unroll
    for (int j = 0; j < 4; ++j) { mrow[j] = -1e30f; lrow[j] = 0.0f; }

    const int nkb = blockIdx.x * 2 + 2;
    for (int kb32 = 0; kb32 < nkb; ++kb32) {
        const int kb = kb32 * 32;
        f32x4 s[2] = {};
        #pragma unroll
        for (int kh = 0; kh < 2; ++kh) {
            const ushortT* kp = qk + (size_t)(kb + kh * 16 + l15) * 2048 + 1024 + h * HD + l4 * 8;
            short8 b0 = *(const short8*)kp;
            short8 b1 = *(const short8*)(kp + 32);
            s[kh] = __builtin_amdgcn_mfma_f32_16x16x32_bf16(aq[0], b0, s[kh], 0, 0, 0);
            s[kh] = __builtin_amdgcn_mfma_f32_16x16x32_bf16(aq[1], b1, s[kh], 0, 0, 0);
        }
        float fac[4];
        #pragma unroll
        for (int j = 0; j < 4; ++j) {
            const int qg = qrow0 + l4 * 4 + j;
            float v0 = s[0][j] * 0.125f;
            float v1 = s[1][j] * 0.125f;
            if (kb + l15 > qg)      v0 = -1e30f;
            if (kb + 16 + l15 > qg) v1 = -1e30f;
            float bm = fmaxf(v0, v1);
            #pragma unroll
            for (int d_ = 1; d_ < 16; d_ <<= 1) bm = fmaxf(bm, __shfl_xor(bm, d_, 64));
            const float mnew = fmaxf(mrow[j], bm);
            const float f = __expf(mrow[j] - mnew);
            const float p0 = __expf(v0 - mnew);
            const float p1 = __expf(v1 - mnew);
            s[0][j] = p0; s[1][j] = p1;
            float rs = p0 + p1;
            #pragma unroll
            for (int d_ = 1; d_ < 16; d_ <<= 1) rs += __shfl_xor(rs, d_, 64);
            lrow[j] = lrow[j] * f + rs;
            mrow[j] = mnew;
            fac[j] = f;
        }
        #pragma unroll
        for (int c = 0; c < 4; ++c)
            #pragma unroll
            for (int j = 0; j < 4; ++j) o[c][j] *= fac[j];

        // P (D-layout) -> per-wave LDS slice -> A-fragment layout (intra-wave dep only)
        #pragma unroll
        for (int kh = 0; kh < 2; ++kh)
            #pragma unroll
            for (int j = 0; j < 4; ++j)
                p_lds[w][l4 * 4 + j][kh * 16 + l15] = (short)f2bf(s[kh][j]);
        short8 pa = *(const short8*)&p_lds[w][l15][l4 * 8];

        #pragma unroll
        for (int c = 0; c < 4; ++c) {
            short8 bv = *(const short8*)(vt + (size_t)(h * HD + c * 16 + l15) * S + kb + l4 * 8);
            o[c] = __builtin_amdgcn_mfma_f32_16x16x32_bf16(pa, bv, o[c], 0, 0, 0);
        }
    }

    #pragma unroll
    for (int c = 0; c < 4; ++c)
        #pragma unroll
        for (int j = 0; j < 4; ++j)
            att[(size_t)(qrow0 + l4 * 4 + j) * D + h * HD + c * 16 + l15] = f2bf(o[c][j] / lrow[j]);
}

// ---------------- fused residual + LayerNorm, dual f32/bf16 out ----------------
__global__ __launch_bounds__(256) void ln_kernel(
    const float* __restrict__ a, const float* __restrict__ b,
    const float* __restrict__ g, const float* __restrict__ bb,
    float* __restrict__ yf, ushortT* __restrict__ yb)
{
    const int row = blockIdx.x;
    const int tid = threadIdx.x;
    const size_t base = (size_t)row * D;
    float x[4]; float s = 0.f, s2 = 0.f;
    #pragma unroll
    for (int i = 0; i < 4; ++i) {
        const int c = tid + i * 256;
        x[i] = a[base + c] + b[base + c];
        s += x[i]; s2 += x[i] * x[i];
    }
    #pragma unroll
    for (int d_ = 1; d_ < 64; d_ <<= 1) {
        s  += __shfl_xor(s,  d_, 64);
        s2 += __shfl_xor(s2, d_, 64);
    }
    __shared__ float rs[4], rs2[4];
    const int wid = tid >> 6, lane = tid & 63;
    if (lane == 0) { rs[wid] = s; rs2[wid] = s2; }
    __syncthreads();
    s = rs[0] + rs[1] + rs[2] + rs[3];
    s2 = rs2[0] + rs2[1] + rs2[2] + rs2[3];
    const float mu = s * (1.0f / D);
    const float var = s2 * (1.0f / D) - mu * mu;
    const float inv = rsqrtf(var + EPS_LN);
    #pragma unroll
    for (int i = 0; i < 4; ++i) {
        const int c = tid + i * 256;
        float v = (x[i] - mu) * inv * g[c] + bb[c];
        yf[base + c] = v;
        yb[base + c] = f2bf(v);
    }
}

// ---------------- launch ----------------
extern "C" void kernel_launch(void* const* d_in, const int* in_sizes, int n_in,
                              void* d_out, int out_size, void* d_ws, size_t ws_size,
                              hipStream_t stream) {
    const int*   ids   = (const int*)  d_in[0];
    const float* emb   = (const float*)d_in[1];
    const float* pos   = (const float*)d_in[2];
    const float* wq    = (const float*)d_in[3];
    const float* bq    = (const float*)d_in[4];
    const float* wk    = (const float*)d_in[5];
    const float* bk    = (const float*)d_in[6];
    const float* wv    = (const float*)d_in[7];
    const float* bv    = (const float*)d_in[8];
    const float* wo    = (const float*)d_in[9];
    const float* bo    = (const float*)d_in[10];
    const float* ln1g  = (const float*)d_in[11];
    const float* ln1b  = (const float*)d_in[12];
    const float* w1    = (const float*)d_in[13];
    const float* b1    = (const float*)d_in[14];
    const float* w2    = (const float*)d_in[15];
    const float* b2    = (const float*)d_in[16];
    const float* ln2g  = (const float*)d_in[17];
    const float* ln2b  = (const float*)d_in[18];
    const float* lmh   = (const float*)d_in[19];
    float* out = (float*)d_out;

    const size_t MB = 1024 * 1024;
    char* w = (char*)d_ws;
    float*   h_f32   = (float*)(w);              //  8 MB  residual stream
    float*   h2_f32  = (float*)(w +  8 * MB);    //  8 MB  post-LN1 residual
    float*   om2_f32 = (float*)(w + 16 * MB);    //  8 MB  o-proj out, then MLP2 out
    ushortT* h_bf    = (ushortT*)(w + 24 * MB);  //  4 MB
    ushortT* h2_bf   = (ushortT*)(w + 28 * MB);  //  4 MB
    ushortT* qk_bf   = (ushortT*)(w + 32 * MB);  //  8 MB  [S][2048]
    ushortT* vt_bf   = (ushortT*)(w + 40 * MB);  //  4 MB  [1024][S]
    ushortT* att_bf  = (ushortT*)(w + 44 * MB);  //  4 MB
    ushortT* m1_bf   = (ushortT*)(w + 48 * MB);  // 16 MB  [S][4096]
    ushortT* wl      = (ushortT*)(w + 64 * MB);  // 24 MB  per-layer bf16 weights
    float*   bqkv    = (float*)(w + 88 * MB);    // 12 KB  packed qkv bias
    ushortT* lmh_bf  = (ushortT*)(w + 89 * MB);  // 65.5 MB

    ushortT* wqkv_bf = wl;
    ushortT* wo_bf   = wl + (size_t)3 * D * D;
    ushortT* w1_bf   = wl + (size_t)4 * D * D;
    ushortT* w2_bf   = wl + (size_t)8 * D * D;

    embed_kernel<<<(S * D) / 256, 256, 0, stream>>>(ids, emb, pos, h_f32, h_bf);

    for (int l = 0; l < NL; ++l) {
        convert_layer<<<6146, 256, 0, stream>>>(wq, wk, wv, wo, w1, w2, bq, bk, bv, l, wl, bqkv);

        // fused QKV: [S x 3072] = h_bf @ wqkv^T ; q,k -> qk_bf, v -> vt_bf (transposed)
        gemm_bf<128, 2, 0, 1><<<16 * 24, 256, 0, stream>>>(h_bf, wqkv_bf, bqkv, qk_bf, vt_bf, 3072, D);

        attn_kernel<<<dim3(S / 64, NH), 256, 0, stream>>>(qk_bf, vt_bf, att_bf);

        gemm_bf<64, 0, 0, 1><<<16 * 16, 256, 0, stream>>>(att_bf, wo_bf, bo + (size_t)l * D, om2_f32, nullptr, D, D);
        ln_kernel<<<S, 256, 0, stream>>>(h_f32, om2_f32, ln1g + (size_t)l * D, ln1b + (size_t)l * D, h2_f32, h2_bf);

        gemm_bf<128, 1, 1, 1><<<16 * 32, 256, 0, stream>>>(h2_bf, w1_bf, b1 + (size_t)l * DFF, m1_bf, nullptr, DFF, D);
        gemm_bf<64, 0, 0, 1><<<16 * 16, 256, 0, stream>>>(m1_bf, w2_bf, b2 + (size_t)l * D, om2_f32, nullptr, D, DFF);
        ln_kernel<<<S, 256, 0, stream>>>(h2_f32, om2_f32, ln2g + (size_t)l * D, ln2b + (size_t)l * D, h_f32, h_bf);
    }

    convert_flat<<<(VOCAB * D) / (256 * 8), 256, 0, stream>>>(lmh, lmh_bf);
    gemm256<0, 0, 0><<<8 * 125, 512, 0, stream>>>(h_bf, lmh_bf, nullptr, out, nullptr, VOCAB, D);
}

// Round 7
// 1152.779 us; speedup vs baseline: 1.3564x; 1.1602x over previous
//
#include <hip/hip_runtime.h>
#include <hip/hip_bf16.h>

// ---- fixed problem geometry ----
#define S 2048
#define D 1024
#define NH 16
#define HD 64
#define NL 4
#define VOCAB 32000
#define DFF 4096
#define EPS_LN 1e-5f

typedef unsigned short ushortT;
typedef __attribute__((ext_vector_type(8))) short short8;
typedef __attribute__((ext_vector_type(4))) unsigned short ushort4v;
typedef __attribute__((ext_vector_type(4))) float f32x4;

__device__ __forceinline__ ushortT f2bf(float f) {
    unsigned u = __float_as_uint(f);
    u += 0x7FFFu + ((u >> 16) & 1u);   // round-to-nearest-even
    return (ushortT)(u >> 16);
}

// async global->LDS, 16 bytes per lane; LDS dest = wave-uniform base + lane*16
__device__ __forceinline__ void gload_lds16(const ushortT* g, ushortT* l) {
    auto gp = (const __attribute__((address_space(1))) unsigned int*)(uintptr_t)g;
    auto lp = (__attribute__((address_space(3))) unsigned int*)(uintptr_t)l;
    __builtin_amdgcn_global_load_lds(gp, lp, 16, 0, 0);
}

__device__ __forceinline__ void cvt8(const float* s, ushortT* d) {
    float4 a = *(const float4*)s;
    float4 b = *(const float4*)(s + 4);
    short8 r;
    r[0] = (short)f2bf(a.x); r[1] = (short)f2bf(a.y);
    r[2] = (short)f2bf(a.z); r[3] = (short)f2bf(a.w);
    r[4] = (short)f2bf(b.x); r[5] = (short)f2bf(b.y);
    r[6] = (short)f2bf(b.z); r[7] = (short)f2bf(b.w);
    *(short8*)d = r;
}

// ---------------- embedding + positional (dual f32/bf16 out) ----------------
__global__ __launch_bounds__(256) void embed_kernel(
    const int* __restrict__ ids, const float* __restrict__ embed,
    const float* __restrict__ pos, float* __restrict__ hf, ushortT* __restrict__ hb)
{
    int i = blockIdx.x * 256 + threadIdx.x;
    int srow = i >> 10;
    int d = i & (D - 1);
    float v = embed[(size_t)ids[srow] * D + d] + pos[i];
    hf[i] = v;
    hb[i] = f2bf(v);
}

// ---------------- per-layer weight conversion f32 -> bf16 (packed) ----------------
__global__ __launch_bounds__(256) void convert_layer(
    const float* __restrict__ wq, const float* __restrict__ wk, const float* __restrict__ wv,
    const float* __restrict__ wo, const float* __restrict__ w1, const float* __restrict__ w2,
    const float* __restrict__ bq, const float* __restrict__ bk, const float* __restrict__ bv,
    int l, ushortT* __restrict__ wl, float* __restrict__ bqkv)
{
    constexpr int R = (D * D) / 8;   // 131072 units of 8 elements
    const int u = blockIdx.x * 256 + threadIdx.x;
    if (u < 12 * R) {
        const float* src;
        if (u < 3 * R) {
            int sub = u >> 17, off = u & (R - 1);
            const float* w = (sub == 0) ? wq : (sub == 1) ? wk : wv;
            src = w + (size_t)l * D * D + (size_t)off * 8;
        } else if (u < 4 * R) {
            src = wo + (size_t)l * D * D + (size_t)(u - 3 * R) * 8;
        } else if (u < 8 * R) {
            src = w1 + (size_t)l * 4 * D * D + (size_t)(u - 4 * R) * 8;
        } else {
            src = w2 + (size_t)l * 4 * D * D + (size_t)(u - 8 * R) * 8;
        }
        cvt8(src, wl + (size_t)u * 8);
    } else if (u < 12 * R + 384) {
        int i = u - 12 * R;
        int sub = i >> 7, off = (i & 127) * 8;
        const float* src = ((sub == 0) ? bq : (sub == 1) ? bk : bv) + (size_t)l * D + off;
        *(float4*)(bqkv + sub * D + off)     = *(const float4*)src;
        *(float4*)(bqkv + sub * D + off + 4) = *(const float4*)(src + 4);
    }
}

__global__ __launch_bounds__(256) void convert_flat(
    const float* __restrict__ src, ushortT* __restrict__ dst)
{
    const size_t u = (size_t)blockIdx.x * 256 + threadIdx.x;   // grid exactly covers n/8
    cvt8(src + u * 8, dst + u * 8);
}

// ---------------- bf16 NT GEMM (128xBN, 2-phase) -- o-proj / fallback ----------------
template<int BN, int OUTMODE, int RELU, int HASBIAS>
__global__ __launch_bounds__(256) void gemm_bf(
    const ushortT* __restrict__ A, const ushortT* __restrict__ B,
    const float* __restrict__ bias, void* __restrict__ Cn, void* __restrict__ Ct,
    int N, int K)
{
    constexpr int WN = BN / 2;
    constexpr int NCT = WN / 16;
    __shared__ alignas(16) ushortT As[128 * 32];
    __shared__ alignas(16) ushortT Bs[BN * 32];

    const int tid = threadIdx.x;
    const int id = blockIdx.x;
    const int brow = (id & 15) * 128;
    const int bcol = (id >> 4) * BN;
    const int lane = tid & 63, wid = tid >> 6;
    const int l15 = lane & 15, l4 = lane >> 4;
    const int wr = wid >> 1, wc = wid & 1;
    const int str = tid >> 2;
    const int stc = (tid & 3) * 8;

    f32x4 acc[4][NCT] = {};

    const ushortT* Ab = A + (size_t)(brow + str) * K + stc;
    const ushortT* Bb = B + (size_t)(bcol + str) * K + stc;
    ushortT* AsD = &As[tid * 8];
    ushortT* BsD = &Bs[tid * 8];

    const int nkb = K >> 5;
    for (int kb = 0; kb < nkb; ++kb) {
        const int ko = kb * 32;
        gload_lds16(Ab + ko, AsD);
        gload_lds16(Ab + ko + (size_t)64 * K, AsD + 2048);
        gload_lds16(Bb + ko, BsD);
        if (BN == 128) gload_lds16(Bb + ko + (size_t)64 * K, BsD + 2048);
        __syncthreads();

        short8 af[4], bfr[NCT];
        #pragma unroll
        for (int rt = 0; rt < 4; ++rt)
            af[rt] = *(const short8*)&As[(wr * 64 + rt * 16 + l15) * 32 + l4 * 8];
        #pragma unroll
        for (int ct = 0; ct < NCT; ++ct)
            bfr[ct] = *(const short8*)&Bs[(wc * WN + ct * 16 + l15) * 32 + l4 * 8];
        #pragma unroll
        for (int rt = 0; rt < 4; ++rt)
            #pragma unroll
            for (int ct = 0; ct < NCT; ++ct)
                acc[rt][ct] = __builtin_amdgcn_mfma_f32_16x16x32_bf16(af[rt], bfr[ct], acc[rt][ct], 0, 0, 0);
        __syncthreads();
    }

    #pragma unroll
    for (int rt = 0; rt < 4; ++rt) {
        const int crow0 = brow + wr * 64 + rt * 16 + l4 * 4;
        #pragma unroll
        for (int ct = 0; ct < NCT; ++ct) {
            const int ccol = bcol + wc * WN + ct * 16 + l15;
            const float bv = HASBIAS ? bias[ccol] : 0.0f;
            if (OUTMODE == 0) {
                float* C = (float*)Cn;
                #pragma unroll
                for (int j = 0; j < 4; ++j) {
                    float v = acc[rt][ct][j] + bv;
                    if (RELU) v = fmaxf(v, 0.0f);
                    C[(size_t)(crow0 + j) * N + ccol] = v;
                }
            } else if (OUTMODE == 1) {
                ushortT* C = (ushortT*)Cn;
                #pragma unroll
                for (int j = 0; j < 4; ++j) {
                    float v = acc[rt][ct][j] + bv;
                    if (RELU) v = fmaxf(v, 0.0f);
                    C[(size_t)(crow0 + j) * N + ccol] = f2bf(v);
                }
            }
        }
    }
}

// ---------------- 256x128 8-wave GEMM, 3-deep LDS ring, counted vmcnt ----------------
// C = A @ B^T (+bias). BM=256, BN=128, BK=64, 512 thr = 8 waves (4m x 2n), wave tile 64x64.
// LDS = 3 bufs x 48KB (A 32K + B 16K), XOR slot-swizzle (inverse swizzle on global src).
// Tile t: reads buf t%3; stages tile t+2 into buf (t+2)%3 (never the read buffer -> no
// phase-position hazards). End of tile: vmcnt(6) (= t+2's 6 loads outstanding, t+1 done).
// 2 phases/tile: p0 {rd A(8)+Blo(4), stage A(t+2) 4x} MFMA c0..1; p1 {rd Bhi(4), stage B 2x} MFMA c2..3.
// Optional split-K (OUTMODE 3): grid = 8*NBn*nsplit, partial outputs at split*2048*N floats.
template<int OUTMODE, int RELU, int HASBIAS>
__global__ __launch_bounds__(512) void gemm256v(
    const ushortT* __restrict__ A, const ushortT* __restrict__ B,
    const float* __restrict__ bias, void* __restrict__ Cn, void* __restrict__ Ct,
    int N, int NBn, int Kloop, int stride)
{
    __shared__ alignas(128) ushortT lds[73728];   // 3 x 24576 ushorts = 144 KiB

    const int tid = threadIdx.x;
    const int bid = blockIdx.x;
    const int cpx = gridDim.x >> 3;                 // grid always %8 == 0
    const int wgid = (bid & 7) * cpx + (bid >> 3);  // XCD-chunked
    const int brow = (wgid & 7) << 8;               // M=2048 -> 8 m-blocks fastest
    const int rest = wgid >> 3;
    const int split = rest / NBn;
    const int bcol = (rest - split * NBn) << 7;
    const int kofs = split * Kloop;

    const int lane = tid & 63, wid = tid >> 6;
    const int l15 = lane & 15, l4 = lane >> 4;
    const int wm = wid >> 1, wn = wid & 1;          // 4m x 2n waves
    const int NT = Kloop >> 6;

    const int srow = tid >> 3;                      // 0..63
    const int scol = ((tid & 7) ^ (srow & 7)) * 8;  // inverse-swizzled source slot
    const ushortT* Asrc = A + (size_t)(brow + srow) * stride + kofs + scol;
    const ushortT* Bsrc = B + (size_t)(bcol + srow) * stride + kofs + scol;

    auto stA = [&](int t, int h) {                  // A half h: rows h*128..h*128+127
        if (t < NT) {
            const int sb = t % 3;
            #pragma unroll
            for (int g = 0; g < 2; ++g)
                gload_lds16(Asrc + (size_t)(h * 128 + g * 64) * stride + (size_t)t * 64,
                            &lds[sb * 24576 + h * 8192 + g * 4096 + tid * 8]);
        }
    };
    auto stB = [&](int t) {                         // B: 128 rows
        if (t < NT) {
            const int sb = t % 3;
            #pragma unroll
            for (int g = 0; g < 2; ++g)
                gload_lds16(Bsrc + (size_t)(g * 64) * stride + (size_t)t * 64,
                            &lds[sb * 24576 + 16384 + g * 4096 + tid * 8]);
        }
    };

    f32x4 acc[4][4] = {};   // [r16][c16]

    // prologue: stage tiles 0 and 1
    stA(0, 0); stA(0, 1); stB(0);
    stA(1, 0); stA(1, 1); stB(1);
    asm volatile("s_waitcnt vmcnt(6)" ::: "memory");   // tile0 resident
    __builtin_amdgcn_s_barrier();

    for (int t = 0; t < NT; ++t) {
        const unsigned abase = (unsigned)(t % 3) * 24576;
        short8 af[4][2], bf2[2][2];

        // ---- p0: read all A-frags + B-lo; stage A(t+2); MFMA c16 0..1 ----
        #pragma unroll
        for (int r16 = 0; r16 < 4; ++r16)
            #pragma unroll
            for (int kk = 0; kk < 2; ++kk)
                af[r16][kk] = *(const short8*)&lds[abase +
                    ((wm * 64 + r16 * 16 + l15) << 6) +
                    ((((kk << 2) + l4) ^ (l15 & 7)) << 3)];
        #pragma unroll
        for (int c16 = 0; c16 < 2; ++c16)
            #pragma unroll
            for (int kk = 0; kk < 2; ++kk)
                bf2[c16][kk] = *(const short8*)&lds[abase + 16384 +
                    ((wn * 64 + c16 * 16 + l15) << 6) +
                    ((((kk << 2) + l4) ^ (l15 & 7)) << 3)];
        stA(t + 2, 0); stA(t + 2, 1);
        __builtin_amdgcn_s_barrier();
        asm volatile("s_waitcnt lgkmcnt(0)" ::: "memory");
        __builtin_amdgcn_sched_barrier(0);
        __builtin_amdgcn_s_setprio(1);
        #pragma unroll
        for (int kk = 0; kk < 2; ++kk)
            #pragma unroll
            for (int r16 = 0; r16 < 4; ++r16)
                #pragma unroll
                for (int c16 = 0; c16 < 2; ++c16)
                    acc[r16][c16] = __builtin_amdgcn_mfma_f32_16x16x32_bf16(
                        af[r16][kk], bf2[c16][kk], acc[r16][c16], 0, 0, 0);
        __builtin_amdgcn_s_setprio(0);
        __builtin_amdgcn_s_barrier();

        // ---- p1: read B-hi; stage B(t+2); MFMA c16 2..3 ----
        #pragma unroll
        for (int c16 = 0; c16 < 2; ++c16)
            #pragma unroll
            for (int kk = 0; kk < 2; ++kk)
                bf2[c16][kk] = *(const short8*)&lds[abase + 16384 +
                    ((wn * 64 + (c16 + 2) * 16 + l15) << 6) +
                    ((((kk << 2) + l4) ^ (l15 & 7)) << 3)];
        stB(t + 2);
        __builtin_amdgcn_s_barrier();
        asm volatile("s_waitcnt lgkmcnt(0)" ::: "memory");
        __builtin_amdgcn_sched_barrier(0);
        __builtin_amdgcn_s_setprio(1);
        #pragma unroll
        for (int kk = 0; kk < 2; ++kk)
            #pragma unroll
            for (int r16 = 0; r16 < 4; ++r16)
                #pragma unroll
                for (int c16 = 0; c16 < 2; ++c16)
                    acc[r16][c16 + 2] = __builtin_amdgcn_mfma_f32_16x16x32_bf16(
                        af[r16][kk], bf2[c16][kk], acc[r16][c16 + 2], 0, 0, 0);
        __builtin_amdgcn_s_setprio(0);
        if (t + 2 < NT) { asm volatile("s_waitcnt vmcnt(6)" ::: "memory"); }
        else            { asm volatile("s_waitcnt vmcnt(0)" ::: "memory"); }
        __builtin_amdgcn_s_barrier();
    }

    // epilogue: C/D layout col = lane&15, row = (lane>>4)*4 + j
    #pragma unroll
    for (int r16 = 0; r16 < 4; ++r16)
    #pragma unroll
    for (int c16 = 0; c16 < 4; ++c16) {
        const int crow0 = brow + wm * 64 + r16 * 16 + l4 * 4;
        const int ccol  = bcol + wn * 64 + c16 * 16 + l15;
        const float bv = HASBIAS ? bias[ccol] : 0.0f;
        if (OUTMODE == 0) {            // f32 nontemporal (lm_head)
            float* C = (float*)Cn;
            #pragma unroll
            for (int j = 0; j < 4; ++j) {
                float v = acc[r16][c16][j] + bv;
                if (RELU) v = fmaxf(v, 0.0f);
                __builtin_nontemporal_store(v, &C[(size_t)(crow0 + j) * N + ccol]);
            }
        } else if (OUTMODE == 1) {     // bf16 (+relu)
            ushortT* C = (ushortT*)Cn;
            #pragma unroll
            for (int j = 0; j < 4; ++j) {
                float v = acc[r16][c16][j] + bv;
                if (RELU) v = fmaxf(v, 0.0f);
                C[(size_t)(crow0 + j) * N + ccol] = f2bf(v);
            }
        } else if (OUTMODE == 2) {     // fused QKV
            if (ccol < 2048) {
                ushortT* C = (ushortT*)Cn;
                #pragma unroll
                for (int j = 0; j < 4; ++j)
                    C[(size_t)(crow0 + j) * 2048 + ccol] = f2bf(acc[r16][c16][j] + bv);
            } else {
                ushortT* C = (ushortT*)Ct;
                ushort4v wv_;
                #pragma unroll
                for (int j = 0; j < 4; ++j) wv_[j] = f2bf(acc[r16][c16][j] + bv);
                *(ushort4v*)&C[(size_t)(ccol - 2048) * S + crow0] = wv_;
            }
        } else {                       // OUTMODE 3: f32 partial (split-K), regular stores
            float* C = (float*)Cn + (size_t)split * 2048 * N;
            #pragma unroll
            for (int j = 0; j < 4; ++j)
                C[(size_t)(crow0 + j) * N + ccol] = acc[r16][c16][j];
        }
    }
}

// ---------------- flash attention (causal), bf16 in/out, barrier-free ----------------
__global__ __launch_bounds__(256) void attn_kernel(
    const ushortT* __restrict__ qk, const ushortT* __restrict__ vt,
    ushortT* __restrict__ att)
{
    const int h = blockIdx.y;
    const int q0 = blockIdx.x * 64;
    const int tid = threadIdx.x;
    const int w = tid >> 6, lane = tid & 63;
    const int l15 = lane & 15, l4 = lane >> 4;
    const int qrow0 = q0 + w * 16;

    __shared__ short p_lds[4][16][48];

    short8 aq[2];
    {
        const ushortT* qp = qk + (size_t)(qrow0 + l15) * 2048 + h * HD + l4 * 8;
        aq[0] = *(const short8*)qp;
        aq[1] = *(const short8*)(qp + 32);
    }

    f32x4 o[4] = {};
    float mrow[4], lrow[4];
    #pragma unroll
    for (int j = 0; j < 4; ++j) { mrow[j] = -1e30f; lrow[j] = 0.0f; }

    const int nkb = blockIdx.x * 2 + 2;
    for (int kb32 = 0; kb32 < nkb; ++kb32) {
        const int kb = kb32 * 32;
        f32x4 s[2] = {};
        #pragma unroll
        for (int kh = 0; kh < 2; ++kh) {
            const ushortT* kp = qk + (size_t)(kb + kh * 16 + l15) * 2048 + 1024 + h * HD + l4 * 8;
            short8 b0 = *(const short8*)kp;
            short8 b1 = *(const short8*)(kp + 32);
            s[kh] = __builtin_amdgcn_mfma_f32_16x16x32_bf16(aq[0], b0, s[kh], 0, 0, 0);
            s[kh] = __builtin_amdgcn_mfma_f32_16x16x32_bf16(aq[1], b1, s[kh], 0, 0, 0);
        }
        float fac[4];
        #pragma unroll
        for (int j = 0; j < 4; ++j) {
            const int qg = qrow0 + l4 * 4 + j;
            float v0 = s[0][j] * 0.125f;
            float v1 = s[1][j] * 0.125f;
            if (kb + l15 > qg)      v0 = -1e30f;
            if (kb + 16 + l15 > qg) v1 = -1e30f;
            float bm = fmaxf(v0, v1);
            #pragma unroll
            for (int d_ = 1; d_ < 16; d_ <<= 1) bm = fmaxf(bm, __shfl_xor(bm, d_, 64));
            const float mnew = fmaxf(mrow[j], bm);
            const float f = __expf(mrow[j] - mnew);
            const float p0 = __expf(v0 - mnew);
            const float p1 = __expf(v1 - mnew);
            s[0][j] = p0; s[1][j] = p1;
            float rs = p0 + p1;
            #pragma unroll
            for (int d_ = 1; d_ < 16; d_ <<= 1) rs += __shfl_xor(rs, d_, 64);
            lrow[j] = lrow[j] * f + rs;
            mrow[j] = mnew;
            fac[j] = f;
        }
        #pragma unroll
        for (int c = 0; c < 4; ++c)
            #pragma unroll
            for (int j = 0; j < 4; ++j) o[c][j] *= fac[j];

        #pragma unroll
        for (int kh = 0; kh < 2; ++kh)
            #pragma unroll
            for (int j = 0; j < 4; ++j)
                p_lds[w][l4 * 4 + j][kh * 16 + l15] = (short)f2bf(s[kh][j]);
        short8 pa = *(const short8*)&p_lds[w][l15][l4 * 8];

        #pragma unroll
        for (int c = 0; c < 4; ++c) {
            short8 bv = *(const short8*)(vt + (size_t)(h * HD + c * 16 + l15) * S + kb + l4 * 8);
            o[c] = __builtin_amdgcn_mfma_f32_16x16x32_bf16(pa, bv, o[c], 0, 0, 0);
        }
    }

    #pragma unroll
    for (int c = 0; c < 4; ++c)
        #pragma unroll
        for (int j = 0; j < 4; ++j)
            att[(size_t)(qrow0 + l4 * 4 + j) * D + h * HD + c * 16 + l15] = f2bf(o[c][j] / lrow[j]);
}

// ---------------- fused residual + NP partials + bias + LayerNorm ----------------
// x = a + (p0[+p1+p2+p3]) + pbias;  y = LN(x)*g + bb   (dual f32/bf16 out)
template<int NP>
__global__ __launch_bounds__(256) void ln_kernel(
    const float* __restrict__ a,
    const float* __restrict__ p0, const float* __restrict__ p1,
    const float* __restrict__ p2, const float* __restrict__ p3,
    const float* __restrict__ pbias,
    const float* __restrict__ g, const float* __restrict__ bb,
    float* __restrict__ yf, ushortT* __restrict__ yb)
{
    const int row = blockIdx.x;
    const int tid = threadIdx.x;
    const size_t base = (size_t)row * D;
    float x[4]; float s = 0.f, s2 = 0.f;
    #pragma unroll
    for (int i = 0; i < 4; ++i) {
        const int c = tid + i * 256;
        float v = a[base + c] + p0[base + c] + pbias[c];
        if (NP > 1) v += p1[base + c] + p2[base + c] + p3[base + c];
        x[i] = v;
        s += v; s2 += v * v;
    }
    #pragma unroll
    for (int d_ = 1; d_ < 64; d_ <<= 1) {
        s  += __shfl_xor(s,  d_, 64);
        s2 += __shfl_xor(s2, d_, 64);
    }
    __shared__ float rs[4], rs2[4];
    const int wid = tid >> 6, lane = tid & 63;
    if (lane == 0) { rs[wid] = s; rs2[wid] = s2; }
    __syncthreads();
    s = rs[0] + rs[1] + rs[2] + rs[3];
    s2 = rs2[0] + rs2[1] + rs2[2] + rs2[3];
    const float mu = s * (1.0f / D);
    const float var = s2 * (1.0f / D) - mu * mu;
    const float inv = rsqrtf(var + EPS_LN);
    #pragma unroll
    for (int i = 0; i < 4; ++i) {
        const int c = tid + i * 256;
        float v = (x[i] - mu) * inv * g[c] + bb[c];
        yf[base + c] = v;
        yb[base + c] = f2bf(v);
    }
}

// ---------------- launch ----------------
extern "C" void kernel_launch(void* const* d_in, const int* in_sizes, int n_in,
                              void* d_out, int out_size, void* d_ws, size_t ws_size,
                              hipStream_t stream) {
    const int*   ids   = (const int*)  d_in[0];
    const float* emb   = (const float*)d_in[1];
    const float* pos   = (const float*)d_in[2];
    const float* wq    = (const float*)d_in[3];
    const float* bq    = (const float*)d_in[4];
    const float* wk    = (const float*)d_in[5];
    const float* bk    = (const float*)d_in[6];
    const float* wv    = (const float*)d_in[7];
    const float* bv    = (const float*)d_in[8];
    const float* wo    = (const float*)d_in[9];
    const float* bo    = (const float*)d_in[10];
    const float* ln1g  = (const float*)d_in[11];
    const float* ln1b  = (const float*)d_in[12];
    const float* w1    = (const float*)d_in[13];
    const float* b1    = (const float*)d_in[14];
    const float* w2    = (const float*)d_in[15];
    const float* b2    = (const float*)d_in[16];
    const float* ln2g  = (const float*)d_in[17];
    const float* ln2b  = (const float*)d_in[18];
    const float* lmh   = (const float*)d_in[19];
    float* out = (float*)d_out;

    const size_t MB = 1024 * 1024;
    char* w = (char*)d_ws;
    float*   h_f32   = (float*)(w);              //  8 MB residual
    float*   h2_f32  = (float*)(w +  8 * MB);    //  8 MB post-LN1 residual
    float*   om2_f32 = (float*)(w + 16 * MB);    //  8 MB o-proj / MLP2 (fallback)
    ushortT* h_bf    = (ushortT*)(w + 24 * MB);  //  4 MB
    ushortT* h2_bf   = (ushortT*)(w + 28 * MB);  //  4 MB
    ushortT* qk_bf   = (ushortT*)(w + 32 * MB);  //  8 MB [S][2048]
    ushortT* vt_bf   = (ushortT*)(w + 40 * MB);  //  4 MB [1024][S]
    ushortT* att_bf  = (ushortT*)(w + 44 * MB);  //  4 MB
    ushortT* m1_bf   = (ushortT*)(w + 48 * MB);  // 16 MB [S][4096]
    ushortT* wl      = (ushortT*)(w + 64 * MB);  // 24 MB per-layer bf16 weights
    float*   bqkv    = (float*)(w + 88 * MB);    // 12 KB packed qkv bias
    ushortT* lmh_bf  = (ushortT*)(w + 89 * MB);  // 65.5 MB
    float*   parts   = (float*)(w + 155 * MB);   // 32 MB split-K partials (if ws allows)

    const bool use_splitk = ws_size >= (size_t)187 * MB;

    ushortT* wqkv_bf = wl;
    ushortT* wo_bf   = wl + (size_t)3 * D * D;
    ushortT* w1_bf   = wl + (size_t)4 * D * D;
    ushortT* w2_bf   = wl + (size_t)8 * D * D;
    const size_t SD = (size_t)S * D;

    embed_kernel<<<(S * D) / 256, 256, 0, stream>>>(ids, emb, pos, h_f32, h_bf);

    for (int l = 0; l < NL; ++l) {
        convert_layer<<<6146, 256, 0, stream>>>(wq, wk, wv, wo, w1, w2, bq, bk, bv, l, wl, bqkv);

        // fused QKV: q,k -> qk_bf [S][2048], v -> vt_bf [D][S] transposed
        gemm256v<2, 0, 1><<<8 * 24, 512, 0, stream>>>(h_bf, wqkv_bf, bqkv, qk_bf, vt_bf,
                                                      3072, 24, D, D);

        attn_kernel<<<dim3(S / 64, NH), 256, 0, stream>>>(qk_bf, vt_bf, att_bf);

        // o-proj (bias folded into ln1)
        gemm_bf<64, 0, 0, 0><<<16 * 16, 256, 0, stream>>>(att_bf, wo_bf, nullptr, om2_f32, nullptr, D, D);
        ln_kernel<1><<<S, 256, 0, stream>>>(h_f32, om2_f32, om2_f32, om2_f32, om2_f32,
                                            bo + (size_t)l * D,
                                            ln1g + (size_t)l * D, ln1b + (size_t)l * D, h2_f32, h2_bf);

        // MLP1 (relu + bias in epilogue)
        gemm256v<1, 1, 1><<<8 * 32, 512, 0, stream>>>(h2_bf, w1_bf, b1 + (size_t)l * DFF, m1_bf, nullptr,
                                                      DFF, 32, D, D);

        // MLP2 (bias folded into ln2)
        if (use_splitk) {
            gemm256v<3, 0, 0><<<8 * 8 * 4, 512, 0, stream>>>(m1_bf, w2_bf, nullptr, parts, nullptr,
                                                             D, 8, D, DFF);
            ln_kernel<4><<<S, 256, 0, stream>>>(h2_f32, parts, parts + SD, parts + 2 * SD, parts + 3 * SD,
                                                b2 + (size_t)l * D,
                                                ln2g + (size_t)l * D, ln2b + (size_t)l * D, h_f32, h_bf);
        } else {
            gemm_bf<64, 0, 0, 0><<<16 * 16, 256, 0, stream>>>(m1_bf, w2_bf, nullptr, om2_f32, nullptr, D, DFF);
            ln_kernel<1><<<S, 256, 0, stream>>>(h2_f32, om2_f32, om2_f32, om2_f32, om2_f32,
                                                b2 + (size_t)l * D,
                                                ln2g + (size_t)l * D, ln2b + (size_t)l * D, h_f32, h_bf);
        }
    }

    convert_flat<<<(VOCAB * D) / (256 * 8), 256, 0, stream>>>(lmh, lmh_bf);
    gemm256v<0, 0, 0><<<8 * 250, 512, 0, stream>>>(h_bf, lmh_bf, nullptr, out, nullptr,
                                                   VOCAB, 250, D, D);
}

// Round 8
// 1142.119 us; speedup vs baseline: 1.3691x; 1.0093x over previous
//
#include <hip/hip_runtime.h>
#include <hip/hip_bf16.h>

// ---- fixed problem geometry ----
#define S 2048
#define D 1024
#define NH 16
#define HD 64
#define NL 4
#define VOCAB 32000
#define DFF 4096
#define EPS_LN 1e-5f

typedef unsigned short ushortT;
typedef __attribute__((ext_vector_type(8))) short short8;
typedef __attribute__((ext_vector_type(4))) unsigned short ushort4v;
typedef __attribute__((ext_vector_type(4))) float f32x4;

__device__ __forceinline__ ushortT f2bf(float f) {
    unsigned u = __float_as_uint(f);
    u += 0x7FFFu + ((u >> 16) & 1u);   // round-to-nearest-even
    return (ushortT)(u >> 16);
}

// async global->LDS, 16 bytes per lane; LDS dest = wave-uniform base + lane*16
__device__ __forceinline__ void gload_lds16(const ushortT* g, ushortT* l) {
    auto gp = (const __attribute__((address_space(1))) unsigned int*)(uintptr_t)g;
    auto lp = (__attribute__((address_space(3))) unsigned int*)(uintptr_t)l;
    __builtin_amdgcn_global_load_lds(gp, lp, 16, 0, 0);
}

__device__ __forceinline__ void cvt8(const float* s, ushortT* d) {
    float4 a = *(const float4*)s;
    float4 b = *(const float4*)(s + 4);
    short8 r;
    r[0] = (short)f2bf(a.x); r[1] = (short)f2bf(a.y);
    r[2] = (short)f2bf(a.z); r[3] = (short)f2bf(a.w);
    r[4] = (short)f2bf(b.x); r[5] = (short)f2bf(b.y);
    r[6] = (short)f2bf(b.z); r[7] = (short)f2bf(b.w);
    *(short8*)d = r;
}

// ---------------- embedding + positional (dual f32/bf16 out) ----------------
__global__ __launch_bounds__(256) void embed_kernel(
    const int* __restrict__ ids, const float* __restrict__ embed,
    const float* __restrict__ pos, float* __restrict__ hf, ushortT* __restrict__ hb)
{
    int i = blockIdx.x * 256 + threadIdx.x;
    int srow = i >> 10;
    int d = i & (D - 1);
    float v = embed[(size_t)ids[srow] * D + d] + pos[i];
    hf[i] = v;
    hb[i] = f2bf(v);
}

// ---------------- per-layer weight conversion f32 -> bf16 (packed) ----------------
__global__ __launch_bounds__(256) void convert_layer(
    const float* __restrict__ wq, const float* __restrict__ wk, const float* __restrict__ wv,
    const float* __restrict__ wo, const float* __restrict__ w1, const float* __restrict__ w2,
    const float* __restrict__ bq, const float* __restrict__ bk, const float* __restrict__ bv,
    int l, ushortT* __restrict__ wl, float* __restrict__ bqkv)
{
    constexpr int R = (D * D) / 8;   // 131072 units of 8 elements
    const int u = blockIdx.x * 256 + threadIdx.x;
    if (u < 12 * R) {
        const float* src;
        if (u < 3 * R) {
            int sub = u >> 17, off = u & (R - 1);
            const float* w = (sub == 0) ? wq : (sub == 1) ? wk : wv;
            src = w + (size_t)l * D * D + (size_t)off * 8;
        } else if (u < 4 * R) {
            src = wo + (size_t)l * D * D + (size_t)(u - 3 * R) * 8;
        } else if (u < 8 * R) {
            src = w1 + (size_t)l * 4 * D * D + (size_t)(u - 4 * R) * 8;
        } else {
            src = w2 + (size_t)l * 4 * D * D + (size_t)(u - 8 * R) * 8;
        }
        cvt8(src, wl + (size_t)u * 8);
    } else if (u < 12 * R + 384) {
        int i = u - 12 * R;
        int sub = i >> 7, off = (i & 127) * 8;
        const float* src = ((sub == 0) ? bq : (sub == 1) ? bk : bv) + (size_t)l * D + off;
        *(float4*)(bqkv + sub * D + off)     = *(const float4*)src;
        *(float4*)(bqkv + sub * D + off + 4) = *(const float4*)(src + 4);
    }
}

__global__ __launch_bounds__(256) void convert_flat(
    const float* __restrict__ src, ushortT* __restrict__ dst)
{
    const size_t u = (size_t)blockIdx.x * 256 + threadIdx.x;   // grid exactly covers n/8
    cvt8(src + u * 8, dst + u * 8);
}

// ---------------- bf16 NT GEMM (128xBN, 2-phase) -- o-proj / fallback ----------------
template<int BN, int OUTMODE, int RELU, int HASBIAS>
__global__ __launch_bounds__(256) void gemm_bf(
    const ushortT* __restrict__ A, const ushortT* __restrict__ B,
    const float* __restrict__ bias, void* __restrict__ Cn, void* __restrict__ Ct,
    int N, int K)
{
    constexpr int WN = BN / 2;
    constexpr int NCT = WN / 16;
    __shared__ alignas(16) ushortT As[128 * 32];
    __shared__ alignas(16) ushortT Bs[BN * 32];

    const int tid = threadIdx.x;
    const int id = blockIdx.x;
    const int brow = (id & 15) * 128;
    const int bcol = (id >> 4) * BN;
    const int lane = tid & 63, wid = tid >> 6;
    const int l15 = lane & 15, l4 = lane >> 4;
    const int wr = wid >> 1, wc = wid & 1;
    const int str = tid >> 2;
    const int stc = (tid & 3) * 8;

    f32x4 acc[4][NCT] = {};

    const ushortT* Ab = A + (size_t)(brow + str) * K + stc;
    const ushortT* Bb = B + (size_t)(bcol + str) * K + stc;
    ushortT* AsD = &As[tid * 8];
    ushortT* BsD = &Bs[tid * 8];

    const int nkb = K >> 5;
    for (int kb = 0; kb < nkb; ++kb) {
        const int ko = kb * 32;
        gload_lds16(Ab + ko, AsD);
        gload_lds16(Ab + ko + (size_t)64 * K, AsD + 2048);
        gload_lds16(Bb + ko, BsD);
        if (BN == 128) gload_lds16(Bb + ko + (size_t)64 * K, BsD + 2048);
        __syncthreads();

        short8 af[4], bfr[NCT];
        #pragma unroll
        for (int rt = 0; rt < 4; ++rt)
            af[rt] = *(const short8*)&As[(wr * 64 + rt * 16 + l15) * 32 + l4 * 8];
        #pragma unroll
        for (int ct = 0; ct < NCT; ++ct)
            bfr[ct] = *(const short8*)&Bs[(wc * WN + ct * 16 + l15) * 32 + l4 * 8];
        #pragma unroll
        for (int rt = 0; rt < 4; ++rt)
            #pragma unroll
            for (int ct = 0; ct < NCT; ++ct)
                acc[rt][ct] = __builtin_amdgcn_mfma_f32_16x16x32_bf16(af[rt], bfr[ct], acc[rt][ct], 0, 0, 0);
        __syncthreads();
    }

    #pragma unroll
    for (int rt = 0; rt < 4; ++rt) {
        const int crow0 = brow + wr * 64 + rt * 16 + l4 * 4;
        #pragma unroll
        for (int ct = 0; ct < NCT; ++ct) {
            const int ccol = bcol + wc * WN + ct * 16 + l15;
            const float bv = HASBIAS ? bias[ccol] : 0.0f;
            if (OUTMODE == 0) {
                float* C = (float*)Cn;
                #pragma unroll
                for (int j = 0; j < 4; ++j) {
                    float v = acc[rt][ct][j] + bv;
                    if (RELU) v = fmaxf(v, 0.0f);
                    C[(size_t)(crow0 + j) * N + ccol] = v;
                }
            } else if (OUTMODE == 1) {
                ushortT* C = (ushortT*)Cn;
                #pragma unroll
                for (int j = 0; j < 4; ++j) {
                    float v = acc[rt][ct][j] + bv;
                    if (RELU) v = fmaxf(v, 0.0f);
                    C[(size_t)(crow0 + j) * N + ccol] = f2bf(v);
                }
            }
        }
    }
}

// ---------------- lm_head: 256x256 4-phase, fragment-reuse, swapped-operand stores ----
// C = A @ B^T, f32 out. BM=BN=256, BK=64, 512 thr = 8 waves (2m x 4n), wave tile 128x64.
// Per K-tile: p0 rd A0(8)+B0(4) -> (0,0); p1 rd B1(4) -> (0,1); p2 rd A1(8) -> (1,1);
// p3 rd none -> (1,0).  24 ds_read_b128 / 64 MFMA per wave per tile.
// Stages: p0->A1(t+1), p1->B1(t+1), p2->B0(t+2), p3->A0(t+2); vmcnt(4)/tile.
// MFMA operands SWAPPED (mfma(B,A)): lane's 4 acc elems = 4 consecutive N -> f32x4 NT store.
__global__ __launch_bounds__(512) void gemm_lmhead(
    const ushortT* __restrict__ A, const ushortT* __restrict__ B,
    float* __restrict__ C, int N)
{
    constexpr int K = 1024;
    constexpr int NT = K >> 6;
    __shared__ alignas(128) ushortT lds[65536];   // 128 KiB

    const int tid = threadIdx.x;
    const int NB = N >> 8;
    const int bid = blockIdx.x;
    const int wgid = (bid & 7) * (NB >> 3) * 8 / 8 * 8 + 0;  // placeholder avoided below
    (void)wgid;
    const int cpx = gridDim.x >> 3;
    const int wg = (bid & 7) * cpx + (bid >> 3);    // XCD-chunked
    const int brow = (wg & 7) << 8;                 // M=2048 -> 8 m-blocks fastest
    const int bcol = (wg >> 3) << 8;

    const int lane = tid & 63;
    const int wid = tid >> 6;
    const int l15 = lane & 15, l4 = lane >> 4;
    const int wm = wid >> 2, wn = wid & 3;          // 2m x 4n waves

    const int srow = tid >> 3;
    const int scol = ((tid & 7) ^ (srow & 7)) * 8;  // inverse-swizzled source slot
    const ushortT* Asrc = A + (size_t)(brow + srow) * K + scol;
    const ushortT* Bsrc = B + (size_t)(bcol + srow) * K + scol;

    auto stA = [&](int t, int h) {
        if (t < NT) {
            const int bb = t & 1;
            #pragma unroll
            for (int g = 0; g < 2; ++g)
                gload_lds16(Asrc + (size_t)(h * 128 + g * 64) * K + (size_t)t * 64,
                            &lds[bb * 32768 + h * 8192 + g * 4096 + tid * 8]);
        }
    };
    auto stB = [&](int t, int h) {
        if (t < NT) {
            const int bb = t & 1;
            #pragma unroll
            for (int g = 0; g < 2; ++g)
                gload_lds16(Bsrc + (size_t)(h * 128 + g * 64) * K + (size_t)t * 64,
                            &lds[bb * 32768 + 16384 + h * 8192 + g * 4096 + tid * 8]);
        }
    };

    f32x4 acc[2][2][4][2] = {};

    stA(0, 0); stB(0, 0); stA(0, 1); stB(0, 1); stB(1, 0); stA(1, 0);
    asm volatile("s_waitcnt vmcnt(4)" ::: "memory");
    __builtin_amdgcn_s_barrier();

#define RD_A(DST, RC)                                                          \
    _Pragma("unroll") for (int r16 = 0; r16 < 4; ++r16)                        \
    _Pragma("unroll") for (int kk = 0; kk < 2; ++kk)                           \
        DST[r16][kk] = *(const short8*)&lds[b * 32768 +                        \
            (((RC) * 128 + wm * 64 + r16 * 16 + l15) << 6) +                   \
            ((((kk << 2) + l4) ^ (l15 & 7)) << 3)];
#define RD_B(DST, CC)                                                          \
    _Pragma("unroll") for (int c16 = 0; c16 < 2; ++c16)                        \
    _Pragma("unroll") for (int kk = 0; kk < 2; ++kk)                           \
        DST[c16][kk] = *(const short8*)&lds[b * 32768 + 16384 +                \
            (((CC) * 128 + wn * 32 + c16 * 16 + l15) << 6) +                   \
            ((((kk << 2) + l4) ^ (l15 & 7)) << 3)];
#define MFMA_Q(AF, BF, RC, CC)                                                 \
    __builtin_amdgcn_s_setprio(1);                                             \
    _Pragma("unroll") for (int kk = 0; kk < 2; ++kk)                           \
    _Pragma("unroll") for (int r16 = 0; r16 < 4; ++r16)                        \
    _Pragma("unroll") for (int c16 = 0; c16 < 2; ++c16)                        \
        acc[RC][CC][r16][c16] = __builtin_amdgcn_mfma_f32_16x16x32_bf16(       \
            BF[c16][kk], AF[r16][kk], acc[RC][CC][r16][c16], 0, 0, 0);         \
    __builtin_amdgcn_s_setprio(0);
#define WAIT_LGKM                                                              \
    asm volatile("s_waitcnt lgkmcnt(0)" ::: "memory");                         \
    __builtin_amdgcn_sched_barrier(0);

    for (int t = 0; t < NT; ++t) {
        const int b = t & 1;
        short8 a_[4][2], b0[2][2], b1[2][2];

        RD_A(a_, 0); RD_B(b0, 0);
        stA(t + 1, 1);
        __builtin_amdgcn_s_barrier();
        WAIT_LGKM;
        MFMA_Q(a_, b0, 0, 0);
        __builtin_amdgcn_s_barrier();

        RD_B(b1, 1);
        stB(t + 1, 1);
        __builtin_amdgcn_s_barrier();
        WAIT_LGKM;
        MFMA_Q(a_, b1, 0, 1);
        __builtin_amdgcn_s_barrier();

        RD_A(a_, 1);
        stB(t + 2, 0);
        __builtin_amdgcn_s_barrier();
        WAIT_LGKM;
        MFMA_Q(a_, b1, 1, 1);
        __builtin_amdgcn_s_barrier();

        stA(t + 2, 0);
        __builtin_amdgcn_s_barrier();
        MFMA_Q(a_, b0, 1, 0);
        if (t < NT - 2) { asm volatile("s_waitcnt vmcnt(4)" ::: "memory"); }
        else            { asm volatile("s_waitcnt vmcnt(0)" ::: "memory"); }
        __builtin_amdgcn_s_barrier();
    }
#undef RD_A
#undef RD_B
#undef MFMA_Q
#undef WAIT_LGKM

    // swapped C/D: lane l15 = seq row (within 16-tile), l4*4+j = 4 consecutive vocab cols
    #pragma unroll
    for (int rc = 0; rc < 2; ++rc)
    #pragma unroll
    for (int cc = 0; cc < 2; ++cc)
    #pragma unroll
    for (int r16 = 0; r16 < 4; ++r16)
    #pragma unroll
    for (int c16 = 0; c16 < 2; ++c16) {
        const int row = brow + rc * 128 + wm * 64 + r16 * 16 + l15;
        const int col = bcol + cc * 128 + wn * 32 + c16 * 16 + l4 * 4;
        __builtin_nontemporal_store(acc[rc][cc][r16][c16],
                                    (f32x4*)&C[(size_t)row * N + col]);
    }
}

// ---------------- 256x128 8-wave GEMM, 3-deep LDS ring, counted vmcnt ----------------
// SWAP=1: mfma(B,A) -> lane holds 4 consecutive N elems -> coalesced vector stores.
template<int OUTMODE, int RELU, int HASBIAS, int SWAP>
__global__ __launch_bounds__(512) void gemm256v(
    const ushortT* __restrict__ A, const ushortT* __restrict__ B,
    const float* __restrict__ bias, void* __restrict__ Cn, void* __restrict__ Ct,
    int N, int NBn, int Kloop, int stride)
{
    __shared__ alignas(128) ushortT lds[73728];   // 3 x 24576 ushorts = 144 KiB

    const int tid = threadIdx.x;
    const int bid = blockIdx.x;
    const int cpx = gridDim.x >> 3;                 // grid always %8 == 0
    const int wgid = (bid & 7) * cpx + (bid >> 3);  // XCD-chunked
    const int brow = (wgid & 7) << 8;               // M=2048 -> 8 m-blocks fastest
    const int rest = wgid >> 3;
    const int split = rest / NBn;
    const int bcol = (rest - split * NBn) << 7;
    const int kofs = split * Kloop;

    const int lane = tid & 63, wid = tid >> 6;
    const int l15 = lane & 15, l4 = lane >> 4;
    const int wm = wid >> 1, wn = wid & 1;          // 4m x 2n waves
    const int NT = Kloop >> 6;

    const int srow = tid >> 3;                      // 0..63
    const int scol = ((tid & 7) ^ (srow & 7)) * 8;  // inverse-swizzled source slot
    const ushortT* Asrc = A + (size_t)(brow + srow) * stride + kofs + scol;
    const ushortT* Bsrc = B + (size_t)(bcol + srow) * stride + kofs + scol;

    auto stA = [&](int t, int h) {
        if (t < NT) {
            const int sb = t % 3;
            #pragma unroll
            for (int g = 0; g < 2; ++g)
                gload_lds16(Asrc + (size_t)(h * 128 + g * 64) * stride + (size_t)t * 64,
                            &lds[sb * 24576 + h * 8192 + g * 4096 + tid * 8]);
        }
    };
    auto stB = [&](int t) {
        if (t < NT) {
            const int sb = t % 3;
            #pragma unroll
            for (int g = 0; g < 2; ++g)
                gload_lds16(Bsrc + (size_t)(g * 64) * stride + (size_t)t * 64,
                            &lds[sb * 24576 + 16384 + g * 4096 + tid * 8]);
        }
    };

    f32x4 acc[4][4] = {};   // [r16][c16]

    stA(0, 0); stA(0, 1); stB(0);
    stA(1, 0); stA(1, 1); stB(1);
    asm volatile("s_waitcnt vmcnt(6)" ::: "memory");
    __builtin_amdgcn_s_barrier();

    for (int t = 0; t < NT; ++t) {
        const unsigned abase = (unsigned)(t % 3) * 24576;
        short8 af[4][2], bf2[2][2];

        // ---- p0: read all A-frags + B-lo; stage A(t+2); MFMA c16 0..1 ----
        #pragma unroll
        for (int r16 = 0; r16 < 4; ++r16)
            #pragma unroll
            for (int kk = 0; kk < 2; ++kk)
                af[r16][kk] = *(const short8*)&lds[abase +
                    ((wm * 64 + r16 * 16 + l15) << 6) +
                    ((((kk << 2) + l4) ^ (l15 & 7)) << 3)];
        #pragma unroll
        for (int c16 = 0; c16 < 2; ++c16)
            #pragma unroll
            for (int kk = 0; kk < 2; ++kk)
                bf2[c16][kk] = *(const short8*)&lds[abase + 16384 +
                    ((wn * 64 + c16 * 16 + l15) << 6) +
                    ((((kk << 2) + l4) ^ (l15 & 7)) << 3)];
        stA(t + 2, 0); stA(t + 2, 1);
        __builtin_amdgcn_s_barrier();
        asm volatile("s_waitcnt lgkmcnt(0)" ::: "memory");
        __builtin_amdgcn_sched_barrier(0);
        __builtin_amdgcn_s_setprio(1);
        #pragma unroll
        for (int kk = 0; kk < 2; ++kk)
            #pragma unroll
            for (int r16 = 0; r16 < 4; ++r16)
                #pragma unroll
                for (int c16 = 0; c16 < 2; ++c16)
                    acc[r16][c16] = SWAP
                        ? __builtin_amdgcn_mfma_f32_16x16x32_bf16(bf2[c16][kk], af[r16][kk], acc[r16][c16], 0, 0, 0)
                        : __builtin_amdgcn_mfma_f32_16x16x32_bf16(af[r16][kk], bf2[c16][kk], acc[r16][c16], 0, 0, 0);
        __builtin_amdgcn_s_setprio(0);
        __builtin_amdgcn_s_barrier();

        // ---- p1: read B-hi; stage B(t+2); MFMA c16 2..3 ----
        #pragma unroll
        for (int c16 = 0; c16 < 2; ++c16)
            #pragma unroll
            for (int kk = 0; kk < 2; ++kk)
                bf2[c16][kk] = *(const short8*)&lds[abase + 16384 +
                    ((wn * 64 + (c16 + 2) * 16 + l15) << 6) +
                    ((((kk << 2) + l4) ^ (l15 & 7)) << 3)];
        stB(t + 2);
        __builtin_amdgcn_s_barrier();
        asm volatile("s_waitcnt lgkmcnt(0)" ::: "memory");
        __builtin_amdgcn_sched_barrier(0);
        __builtin_amdgcn_s_setprio(1);
        #pragma unroll
        for (int kk = 0; kk < 2; ++kk)
            #pragma unroll
            for (int r16 = 0; r16 < 4; ++r16)
                #pragma unroll
                for (int c16 = 0; c16 < 2; ++c16)
                    acc[r16][c16 + 2] = SWAP
                        ? __builtin_amdgcn_mfma_f32_16x16x32_bf16(bf2[c16][kk], af[r16][kk], acc[r16][c16 + 2], 0, 0, 0)
                        : __builtin_amdgcn_mfma_f32_16x16x32_bf16(af[r16][kk], bf2[c16][kk], acc[r16][c16 + 2], 0, 0, 0);
        __builtin_amdgcn_s_setprio(0);
        if (t + 2 < NT) { asm volatile("s_waitcnt vmcnt(6)" ::: "memory"); }
        else            { asm volatile("s_waitcnt vmcnt(0)" ::: "memory"); }
        __builtin_amdgcn_s_barrier();
    }

    #pragma unroll
    for (int r16 = 0; r16 < 4; ++r16)
    #pragma unroll
    for (int c16 = 0; c16 < 4; ++c16) {
        if (SWAP) {
            // lane: row = ..+l15 (seq), col = ..+l4*4 (4 consecutive N)
            const int row = brow + wm * 64 + r16 * 16 + l15;
            const int col = bcol + wn * 64 + c16 * 16 + l4 * 4;
            f32x4 v = acc[r16][c16];
            if (HASBIAS) {
                float4 b4 = *(const float4*)&bias[col];
                v[0] += b4.x; v[1] += b4.y; v[2] += b4.z; v[3] += b4.w;
            }
            if (RELU) {
                #pragma unroll
                for (int j = 0; j < 4; ++j) v[j] = fmaxf(v[j], 0.0f);
            }
            if (OUTMODE == 1) {
                ushort4v o;
                #pragma unroll
                for (int j = 0; j < 4; ++j) o[j] = f2bf(v[j]);
                *(ushort4v*)&((ushortT*)Cn)[(size_t)row * N + col] = o;
            } else if (OUTMODE == 3) {
                float* C = (float*)Cn + (size_t)split * 2048 * N;
                *(f32x4*)&C[(size_t)row * N + col] = v;
            } else {   // OUTMODE 0
                __builtin_nontemporal_store(v, (f32x4*)&((float*)Cn)[(size_t)row * N + col]);
            }
        } else {
            const int crow0 = brow + wm * 64 + r16 * 16 + l4 * 4;
            const int ccol  = bcol + wn * 64 + c16 * 16 + l15;
            const float bv = HASBIAS ? bias[ccol] : 0.0f;
            if (OUTMODE == 2) {        // fused QKV
                if (ccol < 2048) {
                    ushortT* C = (ushortT*)Cn;
                    #pragma unroll
                    for (int j = 0; j < 4; ++j)
                        C[(size_t)(crow0 + j) * 2048 + ccol] = f2bf(acc[r16][c16][j] + bv);
                } else {
                    ushortT* C = (ushortT*)Ct;
                    ushort4v wv_;
                    #pragma unroll
                    for (int j = 0; j < 4; ++j) wv_[j] = f2bf(acc[r16][c16][j] + bv);
                    *(ushort4v*)&C[(size_t)(ccol - 2048) * S + crow0] = wv_;
                }
            } else if (OUTMODE == 1) {
                ushortT* C = (ushortT*)Cn;
                #pragma unroll
                for (int j = 0; j < 4; ++j) {
                    float v = acc[r16][c16][j] + bv;
                    if (RELU) v = fmaxf(v, 0.0f);
                    C[(size_t)(crow0 + j) * N + ccol] = f2bf(v);
                }
            } else {
                float* C = (float*)Cn;
                #pragma unroll
                for (int j = 0; j < 4; ++j) {
                    float v = acc[r16][c16][j] + bv;
                    if (RELU) v = fmaxf(v, 0.0f);
                    C[(size_t)(crow0 + j) * N + ccol] = v;
                }
            }
        }
    }
}

// ---------------- flash attention (causal), bf16 in/out, barrier-free ----------------
__global__ __launch_bounds__(256) void attn_kernel(
    const ushortT* __restrict__ qk, const ushortT* __restrict__ vt,
    ushortT* __restrict__ att)
{
    const int h = blockIdx.y;
    const int q0 = blockIdx.x * 64;
    const int tid = threadIdx.x;
    const int w = tid >> 6, lane = tid & 63;
    const int l15 = lane & 15, l4 = lane >> 4;
    const int qrow0 = q0 + w * 16;

    __shared__ short p_lds[4][16][48];

    short8 aq[2];
    {
        const ushortT* qp = qk + (size_t)(qrow0 + l15) * 2048 + h * HD + l4 * 8;
        aq[0] = *(const short8*)qp;
        aq[1] = *(const short8*)(qp + 32);
    }

    f32x4 o[4] = {};
    float mrow[4], lrow[4];
    #pragma unroll
    for (int j = 0; j < 4; ++j) { mrow[j] = -1e30f; lrow[j] = 0.0f; }

    const int nkb = blockIdx.x * 2 + 2;
    for (int kb32 = 0; kb32 < nkb; ++kb32) {
        const int kb = kb32 * 32;
        f32x4 s[2] = {};
        #pragma unroll
        for (int kh = 0; kh < 2; ++kh) {
            const ushortT* kp = qk + (size_t)(kb + kh * 16 + l15) * 2048 + 1024 + h * HD + l4 * 8;
            short8 b0 = *(const short8*)kp;
            short8 b1 = *(const short8*)(kp + 32);
            s[kh] = __builtin_amdgcn_mfma_f32_16x16x32_bf16(aq[0], b0, s[kh], 0, 0, 0);
            s[kh] = __builtin_amdgcn_mfma_f32_16x16x32_bf16(aq[1], b1, s[kh], 0, 0, 0);
        }
        float fac[4];
        #pragma unroll
        for (int j = 0; j < 4; ++j) {
            const int qg = qrow0 + l4 * 4 + j;
            float v0 = s[0][j] * 0.125f;
            float v1 = s[1][j] * 0.125f;
            if (kb + l15 > qg)      v0 = -1e30f;
            if (kb + 16 + l15 > qg) v1 = -1e30f;
            float bm = fmaxf(v0, v1);
            #pragma unroll
            for (int d_ = 1; d_ < 16; d_ <<= 1) bm = fmaxf(bm, __shfl_xor(bm, d_, 64));
            const float mnew = fmaxf(mrow[j], bm);
            const float f = __expf(mrow[j] - mnew);
            const float p0 = __expf(v0 - mnew);
            const float p1 = __expf(v1 - mnew);
            s[0][j] = p0; s[1][j] = p1;
            float rs = p0 + p1;
            #pragma unroll
            for (int d_ = 1; d_ < 16; d_ <<= 1) rs += __shfl_xor(rs, d_, 64);
            lrow[j] = lrow[j] * f + rs;
            mrow[j] = mnew;
            fac[j] = f;
        }
        #pragma unroll
        for (int c = 0; c < 4; ++c)
            #pragma unroll
            for (int j = 0; j < 4; ++j) o[c][j] *= fac[j];

        #pragma unroll
        for (int kh = 0; kh < 2; ++kh)
            #pragma unroll
            for (int j = 0; j < 4; ++j)
                p_lds[w][l4 * 4 + j][kh * 16 + l15] = (short)f2bf(s[kh][j]);
        short8 pa = *(const short8*)&p_lds[w][l15][l4 * 8];

        #pragma unroll
        for (int c = 0; c < 4; ++c) {
            short8 bv = *(const short8*)(vt + (size_t)(h * HD + c * 16 + l15) * S + kb + l4 * 8);
            o[c] = __builtin_amdgcn_mfma_f32_16x16x32_bf16(pa, bv, o[c], 0, 0, 0);
        }
    }

    #pragma unroll
    for (int c = 0; c < 4; ++c)
        #pragma unroll
        for (int j = 0; j < 4; ++j)
            att[(size_t)(qrow0 + l4 * 4 + j) * D + h * HD + c * 16 + l15] = f2bf(o[c][j] / lrow[j]);
}

// ---------------- fused residual + NP partials + bias + LayerNorm ----------------
template<int NP>
__global__ __launch_bounds__(256) void ln_kernel(
    const float* __restrict__ a,
    const float* __restrict__ p0, const float* __restrict__ p1,
    const float* __restrict__ p2, const float* __restrict__ p3,
    const float* __restrict__ pbias,
    const float* __restrict__ g, const float* __restrict__ bb,
    float* __restrict__ yf, ushortT* __restrict__ yb)
{
    const int row = blockIdx.x;
    const int tid = threadIdx.x;
    const size_t base = (size_t)row * D;
    float x[4]; float s = 0.f, s2 = 0.f;
    #pragma unroll
    for (int i = 0; i < 4; ++i) {
        const int c = tid + i * 256;
        float v = a[base + c] + p0[base + c] + pbias[c];
        if (NP > 1) v += p1[base + c] + p2[base + c] + p3[base + c];
        x[i] = v;
        s += v; s2 += v * v;
    }
    #pragma unroll
    for (int d_ = 1; d_ < 64; d_ <<= 1) {
        s  += __shfl_xor(s,  d_, 64);
        s2 += __shfl_xor(s2, d_, 64);
    }
    __shared__ float rs[4], rs2[4];
    const int wid = tid >> 6, lane = tid & 63;
    if (lane == 0) { rs[wid] = s; rs2[wid] = s2; }
    __syncthreads();
    s = rs[0] + rs[1] + rs[2] + rs[3];
    s2 = rs2[0] + rs2[1] + rs2[2] + rs2[3];
    const float mu = s * (1.0f / D);
    const float var = s2 * (1.0f / D) - mu * mu;
    const float inv = rsqrtf(var + EPS_LN);
    #pragma unroll
    for (int i = 0; i < 4; ++i) {
        const int c = tid + i * 256;
        float v = (x[i] - mu) * inv * g[c] + bb[c];
        yf[base + c] = v;
        yb[base + c] = f2bf(v);
    }
}

// ---------------- launch ----------------
extern "C" void kernel_launch(void* const* d_in, const int* in_sizes, int n_in,
                              void* d_out, int out_size, void* d_ws, size_t ws_size,
                              hipStream_t stream) {
    const int*   ids   = (const int*)  d_in[0];
    const float* emb   = (const float*)d_in[1];
    const float* pos   = (const float*)d_in[2];
    const float* wq    = (const float*)d_in[3];
    const float* bq    = (const float*)d_in[4];
    const float* wk    = (const float*)d_in[5];
    const float* bk    = (const float*)d_in[6];
    const float* wv    = (const float*)d_in[7];
    const float* bv    = (const float*)d_in[8];
    const float* wo    = (const float*)d_in[9];
    const float* bo    = (const float*)d_in[10];
    const float* ln1g  = (const float*)d_in[11];
    const float* ln1b  = (const float*)d_in[12];
    const float* w1    = (const float*)d_in[13];
    const float* b1    = (const float*)d_in[14];
    const float* w2    = (const float*)d_in[15];
    const float* b2    = (const float*)d_in[16];
    const float* ln2g  = (const float*)d_in[17];
    const float* ln2b  = (const float*)d_in[18];
    const float* lmh   = (const float*)d_in[19];
    float* out = (float*)d_out;

    const size_t MB = 1024 * 1024;
    char* w = (char*)d_ws;
    float*   h_f32   = (float*)(w);              //  8 MB residual
    float*   h2_f32  = (float*)(w +  8 * MB);    //  8 MB post-LN1 residual
    float*   om2_f32 = (float*)(w + 16 * MB);    //  8 MB o-proj / MLP2 (fallback)
    ushortT* h_bf    = (ushortT*)(w + 24 * MB);  //  4 MB
    ushortT* h2_bf   = (ushortT*)(w + 28 * MB);  //  4 MB
    ushortT* qk_bf   = (ushortT*)(w + 32 * MB);  //  8 MB [S][2048]
    ushortT* vt_bf   = (ushortT*)(w + 40 * MB);  //  4 MB [1024][S]
    ushortT* att_bf  = (ushortT*)(w + 44 * MB);  //  4 MB
    ushortT* m1_bf   = (ushortT*)(w + 48 * MB);  // 16 MB [S][4096]
    ushortT* wl      = (ushortT*)(w + 64 * MB);  // 24 MB per-layer bf16 weights
    float*   bqkv    = (float*)(w + 88 * MB);    // 12 KB packed qkv bias
    ushortT* lmh_bf  = (ushortT*)(w + 89 * MB);  // 65.5 MB
    float*   parts   = (float*)(w + 155 * MB);   // 32 MB split-K partials (if ws allows)

    const bool use_splitk = ws_size >= (size_t)187 * MB;

    ushortT* wqkv_bf = wl;
    ushortT* wo_bf   = wl + (size_t)3 * D * D;
    ushortT* w1_bf   = wl + (size_t)4 * D * D;
    ushortT* w2_bf   = wl + (size_t)8 * D * D;
    const size_t SD = (size_t)S * D;

    embed_kernel<<<(S * D) / 256, 256, 0, stream>>>(ids, emb, pos, h_f32, h_bf);

    for (int l = 0; l < NL; ++l) {
        convert_layer<<<6146, 256, 0, stream>>>(wq, wk, wv, wo, w1, w2, bq, bk, bv, l, wl, bqkv);

        // fused QKV: q,k -> qk_bf [S][2048], v -> vt_bf [D][S] transposed
        gemm256v<2, 0, 1, 0><<<8 * 24, 512, 0, stream>>>(h_bf, wqkv_bf, bqkv, qk_bf, vt_bf,
                                                         3072, 24, D, D);

        attn_kernel<<<dim3(S / 64, NH), 256, 0, stream>>>(qk_bf, vt_bf, att_bf);

        // o-proj (bias folded into ln1)
        gemm_bf<64, 0, 0, 0><<<16 * 16, 256, 0, stream>>>(att_bf, wo_bf, nullptr, om2_f32, nullptr, D, D);
        ln_kernel<1><<<S, 256, 0, stream>>>(h_f32, om2_f32, om2_f32, om2_f32, om2_f32,
                                            bo + (size_t)l * D,
                                            ln1g + (size_t)l * D, ln1b + (size_t)l * D, h2_f32, h2_bf);

        // MLP1 (relu + bias in epilogue, swapped coalesced bf16 stores)
        gemm256v<1, 1, 1, 1><<<8 * 32, 512, 0, stream>>>(h2_bf, w1_bf, b1 + (size_t)l * DFF, m1_bf, nullptr,
                                                         DFF, 32, D, D);

        // MLP2 (bias folded into ln2)
        if (use_splitk) {
            gemm256v<3, 0, 0, 1><<<8 * 8 * 4, 512, 0, stream>>>(m1_bf, w2_bf, nullptr, parts, nullptr,
                                                                D, 8, D, DFF);
            ln_kernel<4><<<S, 256, 0, stream>>>(h2_f32, parts, parts + SD, parts + 2 * SD, parts + 3 * SD,
                                                b2 + (size_t)l * D,
                                                ln2g + (size_t)l * D, ln2b + (size_t)l * D, h_f32, h_bf);
        } else {
            gemm_bf<64, 0, 0, 0><<<16 * 16, 256, 0, stream>>>(m1_bf, w2_bf, nullptr, om2_f32, nullptr, D, DFF);
            ln_kernel<1><<<S, 256, 0, stream>>>(h2_f32, om2_f32, om2_f32, om2_f32, om2_f32,
                                                b2 + (size_t)l * D,
                                                ln2g + (size_t)l * D, ln2b + (size_t)l * D, h_f32, h_bf);
        }
    }

    convert_flat<<<(VOCAB * D) / (256 * 8), 256, 0, stream>>>(lmh, lmh_bf);
    gemm_lmhead<<<8 * 125, 512, 0, stream>>>(h_bf, lmh_bf, out, VOCAB);
}